// Round 12
// baseline (1520.706 us; speedup 1.0000x reference)
//
#include <hip/hip_runtime.h>
#include <hip/hip_bf16.h>
#include <cstdint>
#include <cstddef>

#define TT     2048
#define DMODEL 1024
#define NHQ    8
#define HD     128
#define KVD    512
#define WIN    384
#define EPSF   1.1920929e-07f
#define SCALE  0.12f

typedef __attribute__((ext_vector_type(8))) short bf16x8;
typedef __attribute__((ext_vector_type(4))) float f32x4;

#define WAITV(N)  asm volatile("s_waitcnt vmcnt(" #N ")" ::: "memory")

__device__ __forceinline__ float b2f(unsigned short u) {
    unsigned int i = ((unsigned int)u) << 16; float f; __builtin_memcpy(&f, &i, 4); return f;
}
__device__ __forceinline__ unsigned short f2b(float f) {
    unsigned int i; __builtin_memcpy(&i, &f, 4);
    unsigned int r = (i + 0x7fffu + ((i >> 16) & 1u)) >> 16;
    return (unsigned short)r;
}

__device__ __forceinline__ void gl_lds16(const unsigned short* g, unsigned short* l) {
    __builtin_amdgcn_global_load_lds(
        (const __attribute__((address_space(1))) unsigned int*)g,
        (__attribute__((address_space(3))) unsigned int*)l, 16, 0, 0);
}
__device__ __forceinline__ void gl_lds16f(const float* g, float* l) {
    __builtin_amdgcn_global_load_lds(
        (const __attribute__((address_space(1))) unsigned int*)g,
        (__attribute__((address_space(3))) unsigned int*)l, 16, 0, 0);
}

// ---------------------------------------------------------------------------
// Weight convert+transpose (R11 version): W f32 [K][N] -> Wt bf16 [N][K].
// gl_lds-staged f32 tile, source-side chunk-XOR swizzle, transpose on read.
// ---------------------------------------------------------------------------
__global__ __launch_bounds__(512)
void convT_k(const float* __restrict__ Wq, const float* __restrict__ Wk,
             const float* __restrict__ Wv, const float* __restrict__ Wo,
             const float* __restrict__ Wfc, const float* __restrict__ Wproj,
             unsigned short* __restrict__ Bqkv, unsigned short* __restrict__ Bo,
             unsigned short* __restrict__ Bfc, unsigned short* __restrict__ Bproj)
{
    __shared__ float lt[128 * 128];
    const int bid = blockIdx.x, tid = threadIdx.x, l = blockIdx.y;

    const float* W; unsigned short* Wt; int K, N, t, nbase;
    if (bid < 64)         { W = Wq    + (size_t)l * 1024 * 1024; Wt = Bqkv  + (size_t)l * 2048 * 1024; K = 1024; N = 1024; t = bid;       nbase = 0;    }
    else if (bid < 96)    { W = Wk    + (size_t)l * 1024 * 512;  Wt = Bqkv  + (size_t)l * 2048 * 1024; K = 1024; N = 512;  t = bid - 64;  nbase = 1024; }
    else if (bid < 128)   { W = Wv    + (size_t)l * 1024 * 512;  Wt = Bqkv  + (size_t)l * 2048 * 1024; K = 1024; N = 512;  t = bid - 96;  nbase = 1536; }
    else if (bid < 192)   { W = Wo    + (size_t)l * 1024 * 1024; Wt = Bo    + (size_t)l * 1024 * 1024; K = 1024; N = 1024; t = bid - 128; nbase = 0;    }
    else if (bid < 448)   { W = Wfc   + (size_t)l * 1024 * 4096; Wt = Bfc   + (size_t)l * 4096 * 1024; K = 1024; N = 4096; t = bid - 192; nbase = 0;    }
    else                  { W = Wproj + (size_t)l * 4096 * 1024; Wt = Bproj + (size_t)l * 1024 * 4096; K = 4096; N = 1024; t = bid - 448; nbase = 0;    }

    const int ktiles = K >> 7;
    const int kt0 = (t % ktiles) * 128, nt0 = (t / ktiles) * 128;

    const int lane = tid & 63, w = tid >> 6;
    const int lhi = lane >> 5;
    const int lc  = lane & 31;

    #pragma unroll
    for (int rd = 0; rd < 8; ++rd) {
        const int k = rd * 16 + w * 2 + lhi;
        const int csrc = lc ^ ((k >> 3) & 31);
        const float* src = W + (size_t)(kt0 + k) * N + nt0 + csrc * 4;
        float* dst = lt + (size_t)(rd * 16 + w * 2) * 128;
        gl_lds16f(src, dst);
    }
    __syncthreads();

    #pragma unroll
    for (int i = 0; i < 4; ++i) {
        int flat = i * 512 + tid;
        int n = flat >> 4, kc = (flat & 15) * 8;
        const int c = ((n >> 2) ^ (kc >> 3)) & 31;
        const float* rp = lt + (size_t)kc * 128 + c * 4 + (n & 3);
        unsigned short o[8];
        #pragma unroll
        for (int j = 0; j < 8; ++j) o[j] = f2b(rp[j * 128]);
        *(uint4*)(Wt + (size_t)(nbase + nt0 + n) * K + kt0 + kc) = *(const uint4*)o;
    }
}

// ---------------------------------------------------------------------------
// gemm4 (proven): 128x128 tile, BK=64, 4 waves, 2 buffers, 2 blocks/CU.
// Used for qkv and o GEMMs. EPI 0: bf16 store at Cp + z*TT*Ntot.
// ---------------------------------------------------------------------------
template<int EPI>
__global__ __launch_bounds__(256, 2)
void gemm4(const unsigned short* __restrict__ A, const unsigned short* __restrict__ Bt,
           unsigned short* __restrict__ Cp, int K, int ksplit, int Ntot)
{
    __shared__ unsigned short As[2 * 128 * 64];
    __shared__ unsigned short Bs[2 * 128 * 64];
    const int BUF = 128 * 64;
    const int tid = threadIdx.x, lane = tid & 63, wv = tid >> 6;

    const int gx = gridDim.x;
    const int nwg = gx * gridDim.y;
    const int ihw = blockIdx.y * gx + blockIdx.x;
    const int q = nwg >> 3, r = nwg & 7;
    const int xcd = ihw & 7, pos = ihw >> 3;
    const int lg = (xcd < r) ? xcd * (q + 1) + pos
                             : r * (q + 1) + (xcd - r) * q + pos;
    const int m0 = (lg % gx) * 128, n0 = (lg / gx) * 128;

    const int kbeg = blockIdx.z * ksplit;
    const int NT = ksplit >> 6;

    const int wr = (wv >> 1) * 64, wc = (wv & 1) * 64;
    const int l15 = lane & 15, g = lane >> 4;
    const int srow = lane >> 3;
    const int sxor = (((lane & 7) ^ srow) << 3);

    const unsigned short* gA0 = A  + (size_t)(m0 + wv * 32 + srow) * K + sxor;
    const unsigned short* gB0 = Bt + (size_t)(n0 + wv * 32 + srow) * K + sxor;

    auto stage = [&](int t) {
        const int b = t & 1;
        const size_t k = (size_t)kbeg + ((size_t)t << 6);
        unsigned short* la = As + b * BUF + (wv * 32) * 64;
        unsigned short* lb = Bs + b * BUF + (wv * 32) * 64;
        #pragma unroll
        for (int c = 0; c < 4; ++c) {
            gl_lds16(gA0 + (size_t)(c * 8) * K + k, la + c * 8 * 64);
            gl_lds16(gB0 + (size_t)(c * 8) * K + k, lb + c * 8 * 64);
        }
    };

    f32x4 acc[4][4] = {};

    stage(0);
    for (int t = 0; t < NT; ++t) {
        if (t + 1 < NT) { stage(t + 1); WAITV(8); }
        else            { WAITV(0); }
        __builtin_amdgcn_s_barrier();

        const unsigned short* Ac = As + (t & 1) * BUF;
        const unsigned short* Bc = Bs + (t & 1) * BUF;
        bf16x8 af[4][2], bfv[4][2];
        #pragma unroll
        for (int mi = 0; mi < 4; ++mi) {
            const int row = wr + mi * 16 + l15, x = row & 7;
            #pragma unroll
            for (int kk = 0; kk < 2; ++kk)
                af[mi][kk] = *(const bf16x8*)(Ac + row * 64 + (((kk * 4 + g) ^ x) << 3));
        }
        #pragma unroll
        for (int ni = 0; ni < 4; ++ni) {
            const int row = wc + ni * 16 + l15, x = row & 7;
            #pragma unroll
            for (int kk = 0; kk < 2; ++kk)
                bfv[ni][kk] = *(const bf16x8*)(Bc + row * 64 + (((kk * 4 + g) ^ x) << 3));
        }
        __builtin_amdgcn_s_setprio(1);
        #pragma unroll
        for (int kk = 0; kk < 2; ++kk)
            #pragma unroll
            for (int mi = 0; mi < 4; ++mi)
                #pragma unroll
                for (int ni = 0; ni < 4; ++ni)
                    acc[mi][ni] = __builtin_amdgcn_mfma_f32_16x16x32_bf16(af[mi][kk], bfv[ni][kk], acc[mi][ni], 0, 0, 0);
        __builtin_amdgcn_s_setprio(0);
        __builtin_amdgcn_s_barrier();
    }

    unsigned short* Cz = Cp + (size_t)blockIdx.z * TT * Ntot;
    #pragma unroll
    for (int mi = 0; mi < 4; ++mi)
        #pragma unroll
        for (int ni = 0; ni < 4; ++ni)
            #pragma unroll
            for (int r2 = 0; r2 < 4; ++r2) {
                int row = m0 + wr + mi * 16 + g * 4 + r2;
                int col = n0 + wc + ni * 16 + l15;
                size_t idx = (size_t)row * Ntot + col;
                float v = acc[mi][ni][r2];
                if (EPI == 0) Cz[idx] = f2b(v);
                else {
                    float z = v > 0.f ? v * v : 0.f;
                    Cz[idx] = f2b(z);
                }
            }
}

// ---------------------------------------------------------------------------
// gemm9 (new, m201-style phase-split): BM=256, BN=128, BK=64, 8 waves
// (2m x 4n, wave-out 128x32, acc[8][2]). 96 KB LDS double-buffer
// (A split in 2 row-halves, B single), 2 phases/K-tile:
//   p0: stage A0,B of t+1 -> WAITV(6) -> bar -> ds A-half0 + B frags
//       -> setprio 16 MFMA -> bar
//   p1: stage A1 of t+1   -> WAITV(6) -> bar -> ds A-half1 frags
//       -> setprio 16 MFMA -> bar
// Half-tile-granular prefetch: every needed half lands >=2 phases after
// issue; vmcnt gates verified (steady 6/6; tail 2/0). T2 swizzle both sides.
// Used for fc (z=1, EPI2) and proj (z=4, EPI0).
// ---------------------------------------------------------------------------
template<int EPI>
__global__ __launch_bounds__(512, 1)
void gemm9(const unsigned short* __restrict__ A, const unsigned short* __restrict__ Bt,
           unsigned short* __restrict__ Cp, int K, int ksplit, int Ntot)
{
    __shared__ unsigned short As[2 * 2 * 128 * 64];   // [buf][mh][128][64]
    __shared__ unsigned short Bs[2 * 128 * 64];       // [buf][128][64]
    const int HBUF = 128 * 64;
    const int tid = threadIdx.x, lane = tid & 63, wv = tid >> 6;
    const int wm = wv >> 2, wn = wv & 3;

    const int gx = gridDim.x;
    const int nwg = gx * gridDim.y;
    const int ihw = blockIdx.y * gx + blockIdx.x;
    const int q = nwg >> 3, r = nwg & 7;
    const int xcd = ihw & 7, pos = ihw >> 3;
    const int lg = (xcd < r) ? xcd * (q + 1) + pos
                             : r * (q + 1) + (xcd - r) * q + pos;
    const int m0 = (lg % gx) * 256, n0 = (lg / gx) * 128;

    const int kbeg = blockIdx.z * ksplit;
    const int NT = ksplit >> 6;

    const int l15 = lane & 15, g = lane >> 4;
    const int srow = tid >> 3;                       // 0..63 (row within 64-row round)
    const int sxor = (((tid & 7) ^ (srow & 7)) << 3);

    const unsigned short* gA = A  + (size_t)(m0 + srow) * K + sxor;
    const unsigned short* gB = Bt + (size_t)(n0 + srow) * K + sxor;

    auto stageA = [&](int t, int mh) {
        const int buf = t & 1;
        const size_t kof = (size_t)kbeg + ((size_t)t << 6);
        #pragma unroll
        for (int c = 0; c < 2; ++c) {
            const unsigned short* src = gA + (size_t)(mh * 128 + c * 64) * K + kof;
            unsigned short* dst = As + buf * (2 * HBUF) + mh * HBUF + (c * 64 + wv * 8) * 64;
            gl_lds16(src, dst);
        }
    };
    auto stageB = [&](int t) {
        const int buf = t & 1;
        const size_t kof = (size_t)kbeg + ((size_t)t << 6);
        #pragma unroll
        for (int c = 0; c < 2; ++c) {
            const unsigned short* src = gB + (size_t)(c * 64) * K + kof;
            unsigned short* dst = Bs + buf * HBUF + (c * 64 + wv * 8) * 64;
            gl_lds16(src, dst);
        }
    };

    f32x4 acc[8][2] = {};
    bf16x8 afr[4][2], bfr[2][2];

    // prologue: all 3 halves of tile 0 (6 loads)
    stageA(0, 0);
    stageB(0);
    stageA(0, 1);

    for (int t = 0; t < NT; ++t) {
        const bool more = (t + 1 < NT);
        const unsigned short* Ab = As + (t & 1) * (2 * HBUF);
        const unsigned short* Bb = Bs + (t & 1) * HBUF;

        // ---- phase 0: A-half0 x B ----
        if (more) { stageA(t + 1, 0); stageB(t + 1); WAITV(6); }
        else      { WAITV(2); }
        __builtin_amdgcn_s_barrier();          // A0(t), B(t) certified for all waves

        #pragma unroll
        for (int mi2 = 0; mi2 < 4; ++mi2) {
            const int row = mi2 * 32 + wm * 16 + l15, x = l15 & 7;
            #pragma unroll
            for (int kk = 0; kk < 2; ++kk)
                afr[mi2][kk] = *(const bf16x8*)(Ab + row * 64 + (((kk * 4 + g) ^ x) << 3));
        }
        #pragma unroll
        for (int ni = 0; ni < 2; ++ni) {
            const int row = wn * 32 + ni * 16 + l15, x = l15 & 7;
            #pragma unroll
            for (int kk = 0; kk < 2; ++kk)
                bfr[ni][kk] = *(const bf16x8*)(Bb + row * 64 + (((kk * 4 + g) ^ x) << 3));
        }
        __builtin_amdgcn_s_setprio(1);
        #pragma unroll
        for (int kk = 0; kk < 2; ++kk)
            #pragma unroll
            for (int mi2 = 0; mi2 < 4; ++mi2)
                #pragma unroll
                for (int ni = 0; ni < 2; ++ni)
                    acc[mi2][ni] = __builtin_amdgcn_mfma_f32_16x16x32_bf16(afr[mi2][kk], bfr[ni][kk], acc[mi2][ni], 0, 0, 0);
        __builtin_amdgcn_s_setprio(0);
        __builtin_amdgcn_s_barrier();          // all phase-0 reads done

        // ---- phase 1: A-half1 x B ----
        if (more) { stageA(t + 1, 1); WAITV(6); }
        else      { WAITV(0); }
        __builtin_amdgcn_s_barrier();          // A1(t) certified

        #pragma unroll
        for (int mi2 = 0; mi2 < 4; ++mi2) {
            const int row = mi2 * 32 + wm * 16 + l15, x = l15 & 7;
            #pragma unroll
            for (int kk = 0; kk < 2; ++kk)
                afr[mi2][kk] = *(const bf16x8*)(Ab + HBUF + row * 64 + (((kk * 4 + g) ^ x) << 3));
        }
        __builtin_amdgcn_s_setprio(1);
        #pragma unroll
        for (int kk = 0; kk < 2; ++kk)
            #pragma unroll
            for (int mi2 = 0; mi2 < 4; ++mi2)
                #pragma unroll
                for (int ni = 0; ni < 2; ++ni)
                    acc[4 + mi2][ni] = __builtin_amdgcn_mfma_f32_16x16x32_bf16(afr[mi2][kk], bfr[ni][kk], acc[4 + mi2][ni], 0, 0, 0);
        __builtin_amdgcn_s_setprio(0);
        __builtin_amdgcn_s_barrier();          // buf(t) reads complete -> next tile may overwrite
    }

    unsigned short* Cz = Cp + (size_t)blockIdx.z * TT * Ntot;
    #pragma unroll
    for (int mi = 0; mi < 8; ++mi)
        #pragma unroll
        for (int ni = 0; ni < 2; ++ni)
            #pragma unroll
            for (int r2 = 0; r2 < 4; ++r2) {
                int row = m0 + (mi >> 2) * 128 + (mi & 3) * 32 + wm * 16 + g * 4 + r2;
                int col = n0 + wn * 32 + ni * 16 + l15;
                size_t idx = (size_t)row * Ntot + col;
                float v = acc[mi][ni][r2];
                if (EPI == 0) Cz[idx] = f2b(v);
                else {
                    float z = v > 0.f ? v * v : 0.f;
                    Cz[idx] = f2b(z);
                }
            }
}

// ---------------------------------------------------------------------------
// Fused residual-reduce + RMSNorm: h += sum_z part[z] (bf16 partials), xn = rms(h)
// ---------------------------------------------------------------------------
__global__ __launch_bounds__(256)
void rmsnormF_k(float* __restrict__ h, const unsigned short* __restrict__ part, int nz,
                unsigned short* __restrict__ xn)
{
    const int t = blockIdx.x, tid = threadIdx.x;
    const size_t idx = (size_t)t * (DMODEL / 4) + tid;
    float4 v = ((const float4*)h)[idx];
    for (int z = 0; z < nz; ++z) {
        ushort4 p = ((const ushort4*)part)[idx + (size_t)z * (TT * DMODEL / 4)];
        v.x += b2f(p.x); v.y += b2f(p.y); v.z += b2f(p.z); v.w += b2f(p.w);
    }
    if (nz > 0) ((float4*)h)[idx] = v;

    float ss = v.x*v.x + v.y*v.y + v.z*v.z + v.w*v.w;
    #pragma unroll
    for (int m = 1; m < 64; m <<= 1) ss += __shfl_xor(ss, m);
    __shared__ float red[4];
    if ((tid & 63) == 0) red[tid >> 6] = ss;
    __syncthreads();
    float tot = red[0] + red[1] + red[2] + red[3];
    float rs = rsqrtf(tot * (1.f / DMODEL) + EPSF);
    unsigned short o[4] = { f2b(v.x*rs), f2b(v.y*rs), f2b(v.z*rs), f2b(v.w*rs) };
    *(ushort4*)(xn + (size_t)t * DMODEL + tid * 4) = *(const ushort4*)o;
}

// ---------------------------------------------------------------------------
__global__ __launch_bounds__(256)
void reduce_add_k(float* __restrict__ h, const unsigned short* __restrict__ part, int nz)
{
    const int i = blockIdx.x * 256 + threadIdx.x;
    float4 hv = ((float4*)h)[i];
    for (int z = 0; z < nz; ++z) {
        ushort4 p = ((const ushort4*)part)[i + (size_t)z * (TT * DMODEL / 4)];
        hv.x += b2f(p.x); hv.y += b2f(p.y); hv.z += b2f(p.z); hv.w += b2f(p.w);
    }
    ((float4*)h)[i] = hv;
}

// ---------------------------------------------------------------------------
// Post-QKV: sums the 2 bf16 split-K partials of the qkv GEMM, then
// rotary + head-RMSNorm on q,k (->bf16); ve-gate + bf16 on v (row-major).
// ---------------------------------------------------------------------------
__global__ __launch_bounds__(256)
void post_qkv_k(const unsigned short* __restrict__ qkv, const unsigned short* __restrict__ xn,
                const float* __restrict__ cosb, const float* __restrict__ sinb,
                const float* __restrict__ Wgate, const float* __restrict__ vel, int hasve,
                unsigned short* __restrict__ qn, unsigned short* __restrict__ kn,
                unsigned short* __restrict__ vrow)
{
    const size_t S2 = (size_t)TT * 2048;
    const int t = blockIdx.x, tid = threadIdx.x;
    __shared__ float cs[64], sn[64], gate[4];
    if (tid < 64) { cs[tid] = cosb[t * 64 + tid]; sn[tid] = sinb[t * 64 + tid]; }
    if (hasve && tid >= 64 && tid < 68) {
        int g = tid - 64; float a = 0.f;
        for (int c = 0; c < 32; ++c) a += b2f(xn[(size_t)t * DMODEL + c]) * Wgate[c * 4 + g];
        gate[g] = 2.f / (1.f + __expf(-a));
    }
    __syncthreads();
    if (tid < 96) {
        const int hid = tid >> 3, sub = tid & 7;
        const unsigned short* src; unsigned short* dst;
        if (hid < 8) { src = qkv + (size_t)t * 2048 + hid * 128;              dst = qn + (size_t)t * 1024 + hid * 128; }
        else         { src = qkv + (size_t)t * 2048 + 1024 + (hid - 8) * 128; dst = kn + (size_t)t * 512 + (hid - 8) * 128; }
        float o1[8], o2[8], ssum = 0.f;
        #pragma unroll
        for (int j = 0; j < 8; ++j) {
            int jj = sub * 8 + j;
            float x1 = b2f(src[jj])      + b2f(src[jj + S2]);
            float x2 = b2f(src[jj + 64]) + b2f(src[jj + 64 + S2]);
            float c = cs[jj], s = sn[jj];
            o1[j] = x1 * c + x2 * s;
            o2[j] = -x1 * s + x2 * c;
            ssum += o1[j]*o1[j] + o2[j]*o2[j];
        }
        ssum += __shfl_xor(ssum, 1); ssum += __shfl_xor(ssum, 2); ssum += __shfl_xor(ssum, 4);
        float rs = rsqrtf(ssum * (1.f / HD) + EPSF);
        #pragma unroll
        for (int j = 0; j < 8; ++j) {
            int jj = sub * 8 + j;
            dst[jj]      = f2b(o1[j] * rs);
            dst[jj + 64] = f2b(o2[j] * rs);
        }
    }
    {
        int d0 = tid * 2;
        #pragma unroll
        for (int j = 0; j < 2; ++j) {
            int d = d0 + j;
            size_t off = (size_t)t * 2048 + 1536 + d;
            float vv = b2f(qkv[off]) + b2f(qkv[off + S2]);
            if (hasve) vv += gate[d >> 7] * vel[(size_t)t * KVD + d];
            vrow[(size_t)t * KVD + d] = f2b(vv);
        }
    }
}

// ---------------------------------------------------------------------------
// vrow [T][KVD] -> vt [KVD][T]  (64x64 LDS tile transpose)
// ---------------------------------------------------------------------------
__global__ __launch_bounds__(256)
void vtrans_k(const unsigned short* __restrict__ vrow, unsigned short* __restrict__ vt)
{
    __shared__ unsigned short lt[64][72];
    const int t0 = blockIdx.x * 64, c0 = blockIdx.y * 64, tid = threadIdx.x;
    #pragma unroll
    for (int i = 0; i < 2; ++i) {
        int r = (tid >> 3) + i * 32;
        int c = (tid & 7) * 8;
        bf16x8 v = *(const bf16x8*)(vrow + (size_t)(t0 + r) * KVD + c0 + c);
        #pragma unroll
        for (int j = 0; j < 8; ++j) lt[c + j][r] = ((unsigned short*)&v)[j];
    }
    __syncthreads();
    #pragma unroll
    for (int i = 0; i < 2; ++i) {
        int r = (tid >> 3) + i * 32;
        int c = (tid & 7) * 8;
        *(bf16x8*)(vt + (size_t)(c0 + r) * TT + t0 + c) = *(const bf16x8*)(&lt[r][c]);
    }
}

// ---------------------------------------------------------------------------
// Flash attention, swapped-QK^T form (R7 version, unchanged).
// ---------------------------------------------------------------------------
__global__ __launch_bounds__(256)
void attn_k(const unsigned short* __restrict__ qn, const unsigned short* __restrict__ kn,
            const unsigned short* __restrict__ vt, unsigned short* __restrict__ y,
            const int* __restrict__ seqlens, int isS)
{
    __shared__ float Ot[4][16][132];
    const int tid = threadIdx.x, w = tid >> 6, lane = tid & 63;
    const int h = blockIdx.y, hkv = h >> 1;
    const int qr = (blockIdx.x * 4 + w) * 16;
    const int s1 = seqlens[1], s2 = seqlens[2], s3 = seqlens[3];
    const int l15 = lane & 15, g = lane >> 4;

    bf16x8 qf[4];
    #pragma unroll
    for (int kk = 0; kk < 4; ++kk)
        qf[kk] = *(const bf16x8*)(qn + (size_t)(qr + l15) * 1024 + h * HD + kk * 32 + g * 8);

    const int row = qr + l15;
    const int drow = (row >= s1) + (row >= s2) + (row >= s3);

    int dq = (qr >= s1) + (qr >= s2) + (qr >= s3);
    int dstart = dq == 0 ? 0 : (dq == 1 ? s1 : (dq == 2 ? s2 : s3));
    int smin = dstart;
    if (isS) { int wlo = qr - WIN; if (wlo > smin) smin = wlo; }
    if (smin < 0) smin = 0;
    const int smax = qr + 16;

    f32x4 acc[8] = {};
    float mrow = -1e30f, lrow = 0.f;

    for (int s0 = smin & ~31; s0 < smax; s0 += 32) {
        f32x4 S[2] = {};
        __builtin_amdgcn_s_setprio(1);
        #pragma unroll
        for (int nb = 0; nb < 2; ++nb) {
            int srow = s0 + nb * 16 + l15;
            #pragma unroll
            for (int kk = 0; kk < 4; ++kk) {
                bf16x8 kf = *(const bf16x8*)(kn + (size_t)srow * KVD + hkv * HD + kk * 32 + g * 8);
                S[nb] = __builtin_amdgcn_mfma_f32_16x16x32_bf16(kf, qf[kk], S[nb], 0, 0, 0);
            }
        }
        __builtin_amdgcn_s_setprio(0);

        float sv[2][4];
        #pragma unroll
        for (int nb = 0; nb < 2; ++nb)
            #pragma unroll
            for (int r = 0; r < 4; ++r) {
                int s = s0 + nb * 16 + 4 * g + r;
                int dcol = (s >= s1) + (s >= s2) + (s >= s3);
                bool valid = (s <= row) && (dcol == drow) && (!isS || (row - s) <= WIN);
                sv[nb][r] = valid ? S[nb][r] * SCALE : -1e30f;
            }

        float pm = sv[0][0];
        #pragma unroll
        for (int r = 1; r < 4; ++r) pm = fmaxf(pm, sv[0][r]);
        #pragma unroll
        for (int r = 0; r < 4; ++r) pm = fmaxf(pm, sv[1][r]);
        pm = fmaxf(pm, __shfl_xor(pm, 16));
        pm = fmaxf(pm, __shfl_xor(pm, 32));
        float mnew = fmaxf(mrow, pm);
        float scl2 = __expf(mrow - mnew);
        float p0[4], p1[4], ps = 0.f;
        #pragma unroll
        for (int r = 0; r < 4; ++r) {
            p0[r] = __expf(sv[0][r] - mnew);
            p1[r] = __expf(sv[1][r] - mnew);
            ps += p0[r] + p1[r];
        }
        ps += __shfl_xor(ps, 16);
        ps += __shfl_xor(ps, 32);
        lrow = lrow * scl2 + ps;
        mrow = mnew;
        #pragma unroll
        for (int nb2 = 0; nb2 < 8; ++nb2) acc[nb2] *= scl2;

        unsigned short pt[8];
        const int base = l15 + ((g & 1) << 5);
        #pragma unroll
        for (int jh = 0; jh < 2; ++jh)
            #pragma unroll
            for (int r = 0; r < 4; ++r) {
                float ta = __shfl(p0[r], base + 16 * jh);
                float tb = __shfl(p1[r], base + 16 * jh);
                pt[jh * 4 + r] = f2b(g >= 2 ? tb : ta);
            }
        bf16x8 pf;
        #pragma unroll
        for (int j = 0; j < 8; ++j) ((unsigned short*)&pf)[j] = pt[j];

        __builtin_amdgcn_s_setprio(1);
        #pragma unroll
        for (int nb2 = 0; nb2 < 8; ++nb2) {
            bf16x8 vf = *(const bf16x8*)(vt + (size_t)(hkv * HD + nb2 * 16 + l15) * TT + s0 + g * 8);
            acc[nb2] = __builtin_amdgcn_mfma_f32_16x16x32_bf16(vf, pf, acc[nb2], 0, 0, 0);
        }
        __builtin_amdgcn_s_setprio(0);
    }

    const float inv = 1.f / lrow;
    #pragma unroll
    for (int nb2 = 0; nb2 < 8; ++nb2)
        #pragma unroll
        for (int r = 0; r < 4; ++r)
            Ot[w][l15][nb2 * 16 + 4 * g + r] = acc[nb2][r] * inv;
    __syncthreads();
    const int qo = lane >> 2, dblk = (lane & 3) * 32;
    #pragma unroll
    for (int i4 = 0; i4 < 4; ++i4) {
        unsigned short ob[8];
        #pragma unroll
        for (int j = 0; j < 8; ++j) ob[j] = f2b(Ot[w][qo][dblk + i4 * 8 + j]);
        *(uint4*)(y + (size_t)(qr + qo) * 1024 + h * HD + dblk + i4 * 8) = *(const uint4*)ob;
    }
}

// ---------------------------------------------------------------------------
extern "C" void kernel_launch(void* const* d_in, const int* in_sizes, int n_in,
                              void* d_out, int out_size, void* d_ws, size_t ws_size,
                              hipStream_t stream)
{
    const float* x       = (const float*)d_in[0];
    const float* ve      = (const float*)d_in[1];
    const float* Wq      = (const float*)d_in[2];
    const float* Wk      = (const float*)d_in[3];
    const float* Wv      = (const float*)d_in[4];
    const float* Wo      = (const float*)d_in[5];
    const float* Wgate   = (const float*)d_in[6];
    const float* Wfc     = (const float*)d_in[7];
    const float* Wproj   = (const float*)d_in[8];
    const float* cosb    = (const float*)d_in[9];
    const float* sinb    = (const float*)d_in[10];
    const int*   seqlens = (const int*)d_in[11];

    float* h = (float*)d_out;
    char* ws = (char*)d_ws;
    unsigned short* xn    = (unsigned short*)(ws);                  // 4 MB
    unsigned short* qn    = (unsigned short*)(ws + (4ull  << 20));  // 4 MB
    unsigned short* kn    = (unsigned short*)(ws + (8ull  << 20));  // 2 MB
    unsigned short* vrow  = (unsigned short*)(ws + (10ull << 20));  // 2 MB
    unsigned short* vt    = (unsigned short*)(ws + (12ull << 20));  // 2 MB
    unsigned short* yb    = (unsigned short*)(ws + (14ull << 20));  // 4 MB
    unsigned short* mb    = (unsigned short*)(ws + (18ull << 20));  // 16 MB
    unsigned short* part  = (unsigned short*)(ws + (34ull << 20));  // 16 MB (bf16 partials)
    unsigned short* Bqkv  = (unsigned short*)(ws + (50ull  << 20)); // 32 MB
    unsigned short* Bo    = (unsigned short*)(ws + (82ull  << 20)); // 16 MB
    unsigned short* Bfc   = (unsigned short*)(ws + (98ull  << 20)); // 64 MB
    unsigned short* Bproj = (unsigned short*)(ws + (162ull << 20)); // 64 MB -> 226 MB

    hipMemcpyAsync(h, x, (size_t)TT * DMODEL * sizeof(float), hipMemcpyDeviceToDevice, stream);

    convT_k<<<dim3(704, 8), 512, 0, stream>>>(Wq, Wk, Wv, Wo, Wfc, Wproj,
                                              Bqkv, Bo, Bfc, Bproj);

    for (int l = 0; l < 8; ++l) {
        int hasve = (l % 2) == 1;
        int isS   = (l % 4) != 3;

        rmsnormF_k<<<TT, 256, 0, stream>>>(h, part, l == 0 ? 0 : 4, xn);

        gemm4<0><<<dim3(16, 16, 2), 256, 0, stream>>>(xn, Bqkv + (size_t)l * 2048 * 1024,
                                                      part, 1024, 512, 2048);

        post_qkv_k<<<TT, 256, 0, stream>>>(part, xn, cosb, sinb,
            Wgate + (size_t)l * 128, ve + (size_t)l * TT * KVD, hasve, qn, kn, vrow);

        vtrans_k<<<dim3(32, 8), 256, 0, stream>>>(vrow, vt);

        attn_k<<<dim3(32, 8), 256, 0, stream>>>(qn, kn, vt, yb, seqlens, isS);

        gemm4<0><<<dim3(16, 8, 4), 256, 0, stream>>>(yb, Bo + (size_t)l * 1024 * 1024,
                                                     part, 1024, 256, 1024);

        rmsnormF_k<<<TT, 256, 0, stream>>>(h, part, 4, xn);

        // fc: gemm9 256x128, z=1, relu^2 epilogue straight to mb
        gemm9<2><<<dim3(8, 32, 1), 512, 0, stream>>>(xn, Bfc + (size_t)l * 4096 * 1024,
                                                     mb, 1024, 1024, 4096);

        // proj: gemm9 256x128, z=4 split-K partials
        gemm9<0><<<dim3(8, 8, 4), 512, 0, stream>>>(mb, Bproj + (size_t)l * 1024 * 4096,
                                                    part, 4096, 1024, 1024);
    }

    reduce_add_k<<<2048, 256, 0, stream>>>(h, part, 4);
}

// Round 13
// 1414.771 us; speedup vs baseline: 1.0749x; 1.0749x over previous
//
#include <hip/hip_runtime.h>
#include <hip/hip_bf16.h>
#include <cstdint>
#include <cstddef>

#define TT     2048
#define DMODEL 1024
#define NHQ    8
#define HD     128
#define KVD    512
#define WIN    384
#define EPSF   1.1920929e-07f
#define SCALE  0.12f

typedef __attribute__((ext_vector_type(8))) short bf16x8;
typedef __attribute__((ext_vector_type(4))) float f32x4;

#define WAITV(N)  asm volatile("s_waitcnt vmcnt(" #N ")" ::: "memory")

__device__ __forceinline__ float b2f(unsigned short u) {
    unsigned int i = ((unsigned int)u) << 16; float f; __builtin_memcpy(&f, &i, 4); return f;
}
__device__ __forceinline__ unsigned short f2b(float f) {
    unsigned int i; __builtin_memcpy(&i, &f, 4);
    unsigned int r = (i + 0x7fffu + ((i >> 16) & 1u)) >> 16;
    return (unsigned short)r;
}

__device__ __forceinline__ void gl_lds16(const unsigned short* g, unsigned short* l) {
    __builtin_amdgcn_global_load_lds(
        (const __attribute__((address_space(1))) unsigned int*)g,
        (__attribute__((address_space(3))) unsigned int*)l, 16, 0, 0);
}
__device__ __forceinline__ void gl_lds16f(const float* g, float* l) {
    __builtin_amdgcn_global_load_lds(
        (const __attribute__((address_space(1))) unsigned int*)g,
        (__attribute__((address_space(3))) unsigned int*)l, 16, 0, 0);
}

// ---------------------------------------------------------------------------
// Weight convert+transpose (R11 version): W f32 [K][N] -> Wt bf16 [N][K].
// gl_lds-staged f32 tile, source-side chunk-XOR swizzle, transpose on read.
// ---------------------------------------------------------------------------
__global__ __launch_bounds__(512)
void convT_k(const float* __restrict__ Wq, const float* __restrict__ Wk,
             const float* __restrict__ Wv, const float* __restrict__ Wo,
             const float* __restrict__ Wfc, const float* __restrict__ Wproj,
             unsigned short* __restrict__ Bqkv, unsigned short* __restrict__ Bo,
             unsigned short* __restrict__ Bfc, unsigned short* __restrict__ Bproj)
{
    __shared__ float lt[128 * 128];
    const int bid = blockIdx.x, tid = threadIdx.x, l = blockIdx.y;

    const float* W; unsigned short* Wt; int K, N, t, nbase;
    if (bid < 64)         { W = Wq    + (size_t)l * 1024 * 1024; Wt = Bqkv  + (size_t)l * 2048 * 1024; K = 1024; N = 1024; t = bid;       nbase = 0;    }
    else if (bid < 96)    { W = Wk    + (size_t)l * 1024 * 512;  Wt = Bqkv  + (size_t)l * 2048 * 1024; K = 1024; N = 512;  t = bid - 64;  nbase = 1024; }
    else if (bid < 128)   { W = Wv    + (size_t)l * 1024 * 512;  Wt = Bqkv  + (size_t)l * 2048 * 1024; K = 1024; N = 512;  t = bid - 96;  nbase = 1536; }
    else if (bid < 192)   { W = Wo    + (size_t)l * 1024 * 1024; Wt = Bo    + (size_t)l * 1024 * 1024; K = 1024; N = 1024; t = bid - 128; nbase = 0;    }
    else if (bid < 448)   { W = Wfc   + (size_t)l * 1024 * 4096; Wt = Bfc   + (size_t)l * 4096 * 1024; K = 1024; N = 4096; t = bid - 192; nbase = 0;    }
    else                  { W = Wproj + (size_t)l * 4096 * 1024; Wt = Bproj + (size_t)l * 1024 * 4096; K = 4096; N = 1024; t = bid - 448; nbase = 0;    }

    const int ktiles = K >> 7;
    const int kt0 = (t % ktiles) * 128, nt0 = (t / ktiles) * 128;

    const int lane = tid & 63, w = tid >> 6;
    const int lhi = lane >> 5;
    const int lc  = lane & 31;

    #pragma unroll
    for (int rd = 0; rd < 8; ++rd) {
        const int k = rd * 16 + w * 2 + lhi;
        const int csrc = lc ^ ((k >> 3) & 31);
        const float* src = W + (size_t)(kt0 + k) * N + nt0 + csrc * 4;
        float* dst = lt + (size_t)(rd * 16 + w * 2) * 128;
        gl_lds16f(src, dst);
    }
    __syncthreads();

    #pragma unroll
    for (int i = 0; i < 4; ++i) {
        int flat = i * 512 + tid;
        int n = flat >> 4, kc = (flat & 15) * 8;
        const int c = ((n >> 2) ^ (kc >> 3)) & 31;
        const float* rp = lt + (size_t)kc * 128 + c * 4 + (n & 3);
        unsigned short o[8];
        #pragma unroll
        for (int j = 0; j < 8; ++j) o[j] = f2b(rp[j * 128]);
        *(uint4*)(Wt + (size_t)(nbase + nt0 + n) * K + kt0 + kc) = *(const uint4*)o;
    }
}

// ---------------------------------------------------------------------------
// gemm4 (settled design): 128x128 tile, BK=64, 4 waves, 2 LDS buffers
// (2 blocks/CU), T2 XOR-swizzle, counted vmcnt(8), setprio on MFMA.
// EPI 0: bf16 store at Cp + z*TT*Ntot; EPI 2: relu^2 -> bf16.
// ---------------------------------------------------------------------------
template<int EPI>
__global__ __launch_bounds__(256, 2)
void gemm4(const unsigned short* __restrict__ A, const unsigned short* __restrict__ Bt,
           unsigned short* __restrict__ Cp, int K, int ksplit, int Ntot)
{
    __shared__ unsigned short As[2 * 128 * 64];
    __shared__ unsigned short Bs[2 * 128 * 64];
    const int BUF = 128 * 64;
    const int tid = threadIdx.x, lane = tid & 63, wv = tid >> 6;

    const int gx = gridDim.x;
    const int nwg = gx * gridDim.y;
    const int ihw = blockIdx.y * gx + blockIdx.x;
    const int q = nwg >> 3, r = nwg & 7;
    const int xcd = ihw & 7, pos = ihw >> 3;
    const int lg = (xcd < r) ? xcd * (q + 1) + pos
                             : r * (q + 1) + (xcd - r) * q + pos;
    const int m0 = (lg % gx) * 128, n0 = (lg / gx) * 128;

    const int kbeg = blockIdx.z * ksplit;
    const int NT = ksplit >> 6;

    const int wr = (wv >> 1) * 64, wc = (wv & 1) * 64;
    const int l15 = lane & 15, g = lane >> 4;
    const int srow = lane >> 3;
    const int sxor = (((lane & 7) ^ srow) << 3);

    const unsigned short* gA0 = A  + (size_t)(m0 + wv * 32 + srow) * K + sxor;
    const unsigned short* gB0 = Bt + (size_t)(n0 + wv * 32 + srow) * K + sxor;

    auto stage = [&](int t) {
        const int b = t & 1;
        const size_t k = (size_t)kbeg + ((size_t)t << 6);
        unsigned short* la = As + b * BUF + (wv * 32) * 64;
        unsigned short* lb = Bs + b * BUF + (wv * 32) * 64;
        #pragma unroll
        for (int c = 0; c < 4; ++c) {
            gl_lds16(gA0 + (size_t)(c * 8) * K + k, la + c * 8 * 64);
            gl_lds16(gB0 + (size_t)(c * 8) * K + k, lb + c * 8 * 64);
        }
    };

    f32x4 acc[4][4] = {};

    stage(0);
    for (int t = 0; t < NT; ++t) {
        if (t + 1 < NT) { stage(t + 1); WAITV(8); }
        else            { WAITV(0); }
        __builtin_amdgcn_s_barrier();

        const unsigned short* Ac = As + (t & 1) * BUF;
        const unsigned short* Bc = Bs + (t & 1) * BUF;
        bf16x8 af[4][2], bfv[4][2];
        #pragma unroll
        for (int mi = 0; mi < 4; ++mi) {
            const int row = wr + mi * 16 + l15, x = row & 7;
            #pragma unroll
            for (int kk = 0; kk < 2; ++kk)
                af[mi][kk] = *(const bf16x8*)(Ac + row * 64 + (((kk * 4 + g) ^ x) << 3));
        }
        #pragma unroll
        for (int ni = 0; ni < 4; ++ni) {
            const int row = wc + ni * 16 + l15, x = row & 7;
            #pragma unroll
            for (int kk = 0; kk < 2; ++kk)
                bfv[ni][kk] = *(const bf16x8*)(Bc + row * 64 + (((kk * 4 + g) ^ x) << 3));
        }
        __builtin_amdgcn_s_setprio(1);
        #pragma unroll
        for (int kk = 0; kk < 2; ++kk)
            #pragma unroll
            for (int mi = 0; mi < 4; ++mi)
                #pragma unroll
                for (int ni = 0; ni < 4; ++ni)
                    acc[mi][ni] = __builtin_amdgcn_mfma_f32_16x16x32_bf16(af[mi][kk], bfv[ni][kk], acc[mi][ni], 0, 0, 0);
        __builtin_amdgcn_s_setprio(0);
        __builtin_amdgcn_s_barrier();
    }

    unsigned short* Cz = Cp + (size_t)blockIdx.z * TT * Ntot;
    #pragma unroll
    for (int mi = 0; mi < 4; ++mi)
        #pragma unroll
        for (int ni = 0; ni < 4; ++ni)
            #pragma unroll
            for (int r2 = 0; r2 < 4; ++r2) {
                int row = m0 + wr + mi * 16 + g * 4 + r2;
                int col = n0 + wc + ni * 16 + l15;
                size_t idx = (size_t)row * Ntot + col;
                float v = acc[mi][ni][r2];
                if (EPI == 0) Cz[idx] = f2b(v);
                else {
                    float z = v > 0.f ? v * v : 0.f;
                    Cz[idx] = f2b(z);
                }
            }
}

// ---------------------------------------------------------------------------
// Fused residual-reduce + RMSNorm: h += sum_z part[z] (bf16 partials), xn = rms(h)
// ---------------------------------------------------------------------------
__global__ __launch_bounds__(256)
void rmsnormF_k(float* __restrict__ h, const unsigned short* __restrict__ part, int nz,
                unsigned short* __restrict__ xn)
{
    const int t = blockIdx.x, tid = threadIdx.x;
    const size_t idx = (size_t)t * (DMODEL / 4) + tid;
    float4 v = ((const float4*)h)[idx];
    for (int z = 0; z < nz; ++z) {
        ushort4 p = ((const ushort4*)part)[idx + (size_t)z * (TT * DMODEL / 4)];
        v.x += b2f(p.x); v.y += b2f(p.y); v.z += b2f(p.z); v.w += b2f(p.w);
    }
    if (nz > 0) ((float4*)h)[idx] = v;

    float ss = v.x*v.x + v.y*v.y + v.z*v.z + v.w*v.w;
    #pragma unroll
    for (int m = 1; m < 64; m <<= 1) ss += __shfl_xor(ss, m);
    __shared__ float red[4];
    if ((tid & 63) == 0) red[tid >> 6] = ss;
    __syncthreads();
    float tot = red[0] + red[1] + red[2] + red[3];
    float rs = rsqrtf(tot * (1.f / DMODEL) + EPSF);
    unsigned short o[4] = { f2b(v.x*rs), f2b(v.y*rs), f2b(v.z*rs), f2b(v.w*rs) };
    *(ushort4*)(xn + (size_t)t * DMODEL + tid * 4) = *(const ushort4*)o;
}

// ---------------------------------------------------------------------------
__global__ __launch_bounds__(256)
void reduce_add_k(float* __restrict__ h, const unsigned short* __restrict__ part, int nz)
{
    const int i = blockIdx.x * 256 + threadIdx.x;
    float4 hv = ((float4*)h)[i];
    for (int z = 0; z < nz; ++z) {
        ushort4 p = ((const ushort4*)part)[i + (size_t)z * (TT * DMODEL / 4)];
        hv.x += b2f(p.x); hv.y += b2f(p.y); hv.z += b2f(p.z); hv.w += b2f(p.w);
    }
    ((float4*)h)[i] = hv;
}

// ---------------------------------------------------------------------------
// Post-QKV: sums the 2 bf16 split-K partials of the qkv GEMM, then
// rotary + head-RMSNorm on q,k (->bf16); ve-gate + bf16 on v (row-major).
// ---------------------------------------------------------------------------
__global__ __launch_bounds__(256)
void post_qkv_k(const unsigned short* __restrict__ qkv, const unsigned short* __restrict__ xn,
                const float* __restrict__ cosb, const float* __restrict__ sinb,
                const float* __restrict__ Wgate, const float* __restrict__ vel, int hasve,
                unsigned short* __restrict__ qn, unsigned short* __restrict__ kn,
                unsigned short* __restrict__ vrow)
{
    const size_t S2 = (size_t)TT * 2048;
    const int t = blockIdx.x, tid = threadIdx.x;
    __shared__ float cs[64], sn[64], gate[4];
    if (tid < 64) { cs[tid] = cosb[t * 64 + tid]; sn[tid] = sinb[t * 64 + tid]; }
    if (hasve && tid >= 64 && tid < 68) {
        int g = tid - 64; float a = 0.f;
        for (int c = 0; c < 32; ++c) a += b2f(xn[(size_t)t * DMODEL + c]) * Wgate[c * 4 + g];
        gate[g] = 2.f / (1.f + __expf(-a));
    }
    __syncthreads();
    if (tid < 96) {
        const int hid = tid >> 3, sub = tid & 7;
        const unsigned short* src; unsigned short* dst;
        if (hid < 8) { src = qkv + (size_t)t * 2048 + hid * 128;              dst = qn + (size_t)t * 1024 + hid * 128; }
        else         { src = qkv + (size_t)t * 2048 + 1024 + (hid - 8) * 128; dst = kn + (size_t)t * 512 + (hid - 8) * 128; }
        float o1[8], o2[8], ssum = 0.f;
        #pragma unroll
        for (int j = 0; j < 8; ++j) {
            int jj = sub * 8 + j;
            float x1 = b2f(src[jj])      + b2f(src[jj + S2]);
            float x2 = b2f(src[jj + 64]) + b2f(src[jj + 64 + S2]);
            float c = cs[jj], s = sn[jj];
            o1[j] = x1 * c + x2 * s;
            o2[j] = -x1 * s + x2 * c;
            ssum += o1[j]*o1[j] + o2[j]*o2[j];
        }
        ssum += __shfl_xor(ssum, 1); ssum += __shfl_xor(ssum, 2); ssum += __shfl_xor(ssum, 4);
        float rs = rsqrtf(ssum * (1.f / HD) + EPSF);
        #pragma unroll
        for (int j = 0; j < 8; ++j) {
            int jj = sub * 8 + j;
            dst[jj]      = f2b(o1[j] * rs);
            dst[jj + 64] = f2b(o2[j] * rs);
        }
    }
    {
        int d0 = tid * 2;
        #pragma unroll
        for (int j = 0; j < 2; ++j) {
            int d = d0 + j;
            size_t off = (size_t)t * 2048 + 1536 + d;
            float vv = b2f(qkv[off]) + b2f(qkv[off + S2]);
            if (hasve) vv += gate[d >> 7] * vel[(size_t)t * KVD + d];
            vrow[(size_t)t * KVD + d] = f2b(vv);
        }
    }
}

// ---------------------------------------------------------------------------
// vrow [T][KVD] -> vt [KVD][T]  (64x64 LDS tile transpose)
// ---------------------------------------------------------------------------
__global__ __launch_bounds__(256)
void vtrans_k(const unsigned short* __restrict__ vrow, unsigned short* __restrict__ vt)
{
    __shared__ unsigned short lt[64][72];
    const int t0 = blockIdx.x * 64, c0 = blockIdx.y * 64, tid = threadIdx.x;
    #pragma unroll
    for (int i = 0; i < 2; ++i) {
        int r = (tid >> 3) + i * 32;
        int c = (tid & 7) * 8;
        bf16x8 v = *(const bf16x8*)(vrow + (size_t)(t0 + r) * KVD + c0 + c);
        #pragma unroll
        for (int j = 0; j < 8; ++j) lt[c + j][r] = ((unsigned short*)&v)[j];
    }
    __syncthreads();
    #pragma unroll
    for (int i = 0; i < 2; ++i) {
        int r = (tid >> 3) + i * 32;
        int c = (tid & 7) * 8;
        *(bf16x8*)(vt + (size_t)(c0 + r) * TT + t0 + c) = *(const bf16x8*)(&lt[r][c]);
    }
}

// ---------------------------------------------------------------------------
// Flash attention, swapped-QK^T form + T13 defer-max (skip O-rescale when
// __all(pm - mrow <= 8): P bounded by e^8, f32 acc has headroom).
// Safety: seqlens are multiples of 512, qr/WIN 16-aligned -> every 32-tile
// has >=1 valid entry per q-row, so mrow is real before any skip.
// ---------------------------------------------------------------------------
__global__ __launch_bounds__(256)
void attn_k(const unsigned short* __restrict__ qn, const unsigned short* __restrict__ kn,
            const unsigned short* __restrict__ vt, unsigned short* __restrict__ y,
            const int* __restrict__ seqlens, int isS)
{
    __shared__ float Ot[4][16][132];
    const int tid = threadIdx.x, w = tid >> 6, lane = tid & 63;
    const int h = blockIdx.y, hkv = h >> 1;
    const int qr = (blockIdx.x * 4 + w) * 16;
    const int s1 = seqlens[1], s2 = seqlens[2], s3 = seqlens[3];
    const int l15 = lane & 15, g = lane >> 4;

    bf16x8 qf[4];
    #pragma unroll
    for (int kk = 0; kk < 4; ++kk)
        qf[kk] = *(const bf16x8*)(qn + (size_t)(qr + l15) * 1024 + h * HD + kk * 32 + g * 8);

    const int row = qr + l15;
    const int drow = (row >= s1) + (row >= s2) + (row >= s3);

    int dq = (qr >= s1) + (qr >= s2) + (qr >= s3);
    int dstart = dq == 0 ? 0 : (dq == 1 ? s1 : (dq == 2 ? s2 : s3));
    int smin = dstart;
    if (isS) { int wlo = qr - WIN; if (wlo > smin) smin = wlo; }
    if (smin < 0) smin = 0;
    const int smax = qr + 16;

    f32x4 acc[8] = {};
    float mrow = -1e30f, lrow = 0.f;

    for (int s0 = smin & ~31; s0 < smax; s0 += 32) {
        f32x4 S[2] = {};
        __builtin_amdgcn_s_setprio(1);
        #pragma unroll
        for (int nb = 0; nb < 2; ++nb) {
            int srow = s0 + nb * 16 + l15;
            #pragma unroll
            for (int kk = 0; kk < 4; ++kk) {
                bf16x8 kf = *(const bf16x8*)(kn + (size_t)srow * KVD + hkv * HD + kk * 32 + g * 8);
                S[nb] = __builtin_amdgcn_mfma_f32_16x16x32_bf16(kf, qf[kk], S[nb], 0, 0, 0);
            }
        }
        __builtin_amdgcn_s_setprio(0);

        float sv[2][4];
        #pragma unroll
        for (int nb = 0; nb < 2; ++nb)
            #pragma unroll
            for (int r = 0; r < 4; ++r) {
                int s = s0 + nb * 16 + 4 * g + r;
                int dcol = (s >= s1) + (s >= s2) + (s >= s3);
                bool valid = (s <= row) && (dcol == drow) && (!isS || (row - s) <= WIN);
                sv[nb][r] = valid ? S[nb][r] * SCALE : -1e30f;
            }

        float pm = sv[0][0];
        #pragma unroll
        for (int r = 1; r < 4; ++r) pm = fmaxf(pm, sv[0][r]);
        #pragma unroll
        for (int r = 0; r < 4; ++r) pm = fmaxf(pm, sv[1][r]);
        pm = fmaxf(pm, __shfl_xor(pm, 16));
        pm = fmaxf(pm, __shfl_xor(pm, 32));

        float p0[4], p1[4];
        if (__all(pm - mrow <= 8.f)) {
            // defer-max: keep mrow, no acc rescale; P bounded by e^8
            float ps = 0.f;
            #pragma unroll
            for (int r = 0; r < 4; ++r) {
                p0[r] = __expf(sv[0][r] - mrow);
                p1[r] = __expf(sv[1][r] - mrow);
                ps += p0[r] + p1[r];
            }
            ps += __shfl_xor(ps, 16);
            ps += __shfl_xor(ps, 32);
            lrow += ps;
        } else {
            float mnew = fmaxf(mrow, pm);
            float scl2 = __expf(mrow - mnew);
            float ps = 0.f;
            #pragma unroll
            for (int r = 0; r < 4; ++r) {
                p0[r] = __expf(sv[0][r] - mnew);
                p1[r] = __expf(sv[1][r] - mnew);
                ps += p0[r] + p1[r];
            }
            ps += __shfl_xor(ps, 16);
            ps += __shfl_xor(ps, 32);
            lrow = lrow * scl2 + ps;
            mrow = mnew;
            #pragma unroll
            for (int nb2 = 0; nb2 < 8; ++nb2) acc[nb2] *= scl2;
        }

        unsigned short pt[8];
        const int base = l15 + ((g & 1) << 5);
        #pragma unroll
        for (int jh = 0; jh < 2; ++jh)
            #pragma unroll
            for (int r = 0; r < 4; ++r) {
                float ta = __shfl(p0[r], base + 16 * jh);
                float tb = __shfl(p1[r], base + 16 * jh);
                pt[jh * 4 + r] = f2b(g >= 2 ? tb : ta);
            }
        bf16x8 pf;
        #pragma unroll
        for (int j = 0; j < 8; ++j) ((unsigned short*)&pf)[j] = pt[j];

        __builtin_amdgcn_s_setprio(1);
        #pragma unroll
        for (int nb2 = 0; nb2 < 8; ++nb2) {
            bf16x8 vf = *(const bf16x8*)(vt + (size_t)(hkv * HD + nb2 * 16 + l15) * TT + s0 + g * 8);
            acc[nb2] = __builtin_amdgcn_mfma_f32_16x16x32_bf16(vf, pf, acc[nb2], 0, 0, 0);
        }
        __builtin_amdgcn_s_setprio(0);
    }

    const float inv = 1.f / lrow;
    #pragma unroll
    for (int nb2 = 0; nb2 < 8; ++nb2)
        #pragma unroll
        for (int r = 0; r < 4; ++r)
            Ot[w][l15][nb2 * 16 + 4 * g + r] = acc[nb2][r] * inv;
    __syncthreads();
    const int qo = lane >> 2, dblk = (lane & 3) * 32;
    #pragma unroll
    for (int i4 = 0; i4 < 4; ++i4) {
        unsigned short ob[8];
        #pragma unroll
        for (int j = 0; j < 8; ++j) ob[j] = f2b(Ot[w][qo][dblk + i4 * 8 + j]);
        *(uint4*)(y + (size_t)(qr + qo) * 1024 + h * HD + dblk + i4 * 8) = *(const uint4*)ob;
    }
}

// ---------------------------------------------------------------------------
extern "C" void kernel_launch(void* const* d_in, const int* in_sizes, int n_in,
                              void* d_out, int out_size, void* d_ws, size_t ws_size,
                              hipStream_t stream)
{
    const float* x       = (const float*)d_in[0];
    const float* ve      = (const float*)d_in[1];
    const float* Wq      = (const float*)d_in[2];
    const float* Wk      = (const float*)d_in[3];
    const float* Wv      = (const float*)d_in[4];
    const float* Wo      = (const float*)d_in[5];
    const float* Wgate   = (const float*)d_in[6];
    const float* Wfc     = (const float*)d_in[7];
    const float* Wproj   = (const float*)d_in[8];
    const float* cosb    = (const float*)d_in[9];
    const float* sinb    = (const float*)d_in[10];
    const int*   seqlens = (const int*)d_in[11];

    float* h = (float*)d_out;
    char* ws = (char*)d_ws;
    unsigned short* xn    = (unsigned short*)(ws);                  // 4 MB
    unsigned short* qn    = (unsigned short*)(ws + (4ull  << 20));  // 4 MB
    unsigned short* kn    = (unsigned short*)(ws + (8ull  << 20));  // 2 MB
    unsigned short* vrow  = (unsigned short*)(ws + (10ull << 20));  // 2 MB
    unsigned short* vt    = (unsigned short*)(ws + (12ull << 20));  // 2 MB
    unsigned short* yb    = (unsigned short*)(ws + (14ull << 20));  // 4 MB
    unsigned short* mb    = (unsigned short*)(ws + (18ull << 20));  // 16 MB
    unsigned short* part  = (unsigned short*)(ws + (34ull << 20));  // 16 MB (bf16 partials)
    unsigned short* Bqkv  = (unsigned short*)(ws + (50ull  << 20)); // 32 MB
    unsigned short* Bo    = (unsigned short*)(ws + (82ull  << 20)); // 16 MB
    unsigned short* Bfc   = (unsigned short*)(ws + (98ull  << 20)); // 64 MB
    unsigned short* Bproj = (unsigned short*)(ws + (162ull << 20)); // 64 MB -> 226 MB

    hipMemcpyAsync(h, x, (size_t)TT * DMODEL * sizeof(float), hipMemcpyDeviceToDevice, stream);

    convT_k<<<dim3(704, 8), 512, 0, stream>>>(Wq, Wk, Wv, Wo, Wfc, Wproj,
                                              Bqkv, Bo, Bfc, Bproj);

    for (int l = 0; l < 8; ++l) {
        int hasve = (l % 2) == 1;
        int isS   = (l % 4) != 3;

        rmsnormF_k<<<TT, 256, 0, stream>>>(h, part, l == 0 ? 0 : 4, xn);

        gemm4<0><<<dim3(16, 16, 2), 256, 0, stream>>>(xn, Bqkv + (size_t)l * 2048 * 1024,
                                                      part, 1024, 512, 2048);

        post_qkv_k<<<TT, 256, 0, stream>>>(part, xn, cosb, sinb,
            Wgate + (size_t)l * 128, ve + (size_t)l * TT * KVD, hasve, qn, kn, vrow);

        vtrans_k<<<dim3(32, 8), 256, 0, stream>>>(vrow, vt);

        attn_k<<<dim3(32, 8), 256, 0, stream>>>(qn, kn, vt, yb, seqlens, isS);

        gemm4<0><<<dim3(16, 8, 4), 256, 0, stream>>>(yb, Bo + (size_t)l * 1024 * 1024,
                                                     part, 1024, 256, 1024);

        rmsnormF_k<<<TT, 256, 0, stream>>>(h, part, 4, xn);

        gemm4<2><<<dim3(16, 32, 1), 256, 0, stream>>>(xn, Bfc + (size_t)l * 4096 * 1024,
                                                      mb, 1024, 1024, 4096);

        gemm4<0><<<dim3(16, 8, 4), 256, 0, stream>>>(mb, Bproj + (size_t)l * 1024 * 4096,
                                                     part, 4096, 1024, 1024);
    }

    reduce_add_k<<<2048, 256, 0, stream>>>(h, part, 4);
}

// Round 14
// 1395.407 us; speedup vs baseline: 1.0898x; 1.0139x over previous
//
#include <hip/hip_runtime.h>
#include <hip/hip_bf16.h>
#include <cstdint>
#include <cstddef>

#define TT     2048
#define DMODEL 1024
#define NHQ    8
#define HD     128
#define KVD    512
#define WIN    384
#define EPSF   1.1920929e-07f
#define SCALE  0.12f

typedef __attribute__((ext_vector_type(8))) short bf16x8;
typedef __attribute__((ext_vector_type(4))) float f32x4;

#define WAITV(N)  asm volatile("s_waitcnt vmcnt(" #N ")" ::: "memory")

__device__ __forceinline__ float b2f(unsigned short u) {
    unsigned int i = ((unsigned int)u) << 16; float f; __builtin_memcpy(&f, &i, 4); return f;
}
__device__ __forceinline__ unsigned short f2b(float f) {
    unsigned int i; __builtin_memcpy(&i, &f, 4);
    unsigned int r = (i + 0x7fffu + ((i >> 16) & 1u)) >> 16;
    return (unsigned short)r;
}

__device__ __forceinline__ void gl_lds16(const unsigned short* g, unsigned short* l) {
    __builtin_amdgcn_global_load_lds(
        (const __attribute__((address_space(1))) unsigned int*)g,
        (__attribute__((address_space(3))) unsigned int*)l, 16, 0, 0);
}
__device__ __forceinline__ void gl_lds16f(const float* g, float* l) {
    __builtin_amdgcn_global_load_lds(
        (const __attribute__((address_space(1))) unsigned int*)g,
        (__attribute__((address_space(3))) unsigned int*)l, 16, 0, 0);
}

// ---------------------------------------------------------------------------
// Weight convert+transpose (R11 version): W f32 [K][N] -> Wt bf16 [N][K].
// gl_lds-staged f32 tile, source-side chunk-XOR swizzle, transpose on read.
// ---------------------------------------------------------------------------
__global__ __launch_bounds__(512)
void convT_k(const float* __restrict__ Wq, const float* __restrict__ Wk,
             const float* __restrict__ Wv, const float* __restrict__ Wo,
             const float* __restrict__ Wfc, const float* __restrict__ Wproj,
             unsigned short* __restrict__ Bqkv, unsigned short* __restrict__ Bo,
             unsigned short* __restrict__ Bfc, unsigned short* __restrict__ Bproj)
{
    __shared__ float lt[128 * 128];
    const int bid = blockIdx.x, tid = threadIdx.x, l = blockIdx.y;

    const float* W; unsigned short* Wt; int K, N, t, nbase;
    if (bid < 64)         { W = Wq    + (size_t)l * 1024 * 1024; Wt = Bqkv  + (size_t)l * 2048 * 1024; K = 1024; N = 1024; t = bid;       nbase = 0;    }
    else if (bid < 96)    { W = Wk    + (size_t)l * 1024 * 512;  Wt = Bqkv  + (size_t)l * 2048 * 1024; K = 1024; N = 512;  t = bid - 64;  nbase = 1024; }
    else if (bid < 128)   { W = Wv    + (size_t)l * 1024 * 512;  Wt = Bqkv  + (size_t)l * 2048 * 1024; K = 1024; N = 512;  t = bid - 96;  nbase = 1536; }
    else if (bid < 192)   { W = Wo    + (size_t)l * 1024 * 1024; Wt = Bo    + (size_t)l * 1024 * 1024; K = 1024; N = 1024; t = bid - 128; nbase = 0;    }
    else if (bid < 448)   { W = Wfc   + (size_t)l * 1024 * 4096; Wt = Bfc   + (size_t)l * 4096 * 1024; K = 1024; N = 4096; t = bid - 192; nbase = 0;    }
    else                  { W = Wproj + (size_t)l * 4096 * 1024; Wt = Bproj + (size_t)l * 1024 * 4096; K = 4096; N = 1024; t = bid - 448; nbase = 0;    }

    const int ktiles = K >> 7;
    const int kt0 = (t % ktiles) * 128, nt0 = (t / ktiles) * 128;

    const int lane = tid & 63, w = tid >> 6;
    const int lhi = lane >> 5;
    const int lc  = lane & 31;

    #pragma unroll
    for (int rd = 0; rd < 8; ++rd) {
        const int k = rd * 16 + w * 2 + lhi;
        const int csrc = lc ^ ((k >> 3) & 31);
        const float* src = W + (size_t)(kt0 + k) * N + nt0 + csrc * 4;
        float* dst = lt + (size_t)(rd * 16 + w * 2) * 128;
        gl_lds16f(src, dst);
    }
    __syncthreads();

    #pragma unroll
    for (int i = 0; i < 4; ++i) {
        int flat = i * 512 + tid;
        int n = flat >> 4, kc = (flat & 15) * 8;
        const int c = ((n >> 2) ^ (kc >> 3)) & 31;
        const float* rp = lt + (size_t)kc * 128 + c * 4 + (n & 3);
        unsigned short o[8];
        #pragma unroll
        for (int j = 0; j < 8; ++j) o[j] = f2b(rp[j * 128]);
        *(uint4*)(Wt + (size_t)(nbase + nt0 + n) * K + kt0 + kc) = *(const uint4*)o;
    }
}

// ---------------------------------------------------------------------------
// gemm4 (settled design): 128x128 tile, BK=64, 4 waves, 2 LDS buffers
// (2 blocks/CU), T2 XOR-swizzle, counted vmcnt(8), setprio on MFMA.
// EPI 0: bf16 store at Cp + z*TT*Ntot; EPI 2: relu^2 -> bf16.
// ---------------------------------------------------------------------------
template<int EPI>
__global__ __launch_bounds__(256, 2)
void gemm4(const unsigned short* __restrict__ A, const unsigned short* __restrict__ Bt,
           unsigned short* __restrict__ Cp, int K, int ksplit, int Ntot)
{
    __shared__ unsigned short As[2 * 128 * 64];
    __shared__ unsigned short Bs[2 * 128 * 64];
    const int BUF = 128 * 64;
    const int tid = threadIdx.x, lane = tid & 63, wv = tid >> 6;

    const int gx = gridDim.x;
    const int nwg = gx * gridDim.y;
    const int ihw = blockIdx.y * gx + blockIdx.x;
    const int q = nwg >> 3, r = nwg & 7;
    const int xcd = ihw & 7, pos = ihw >> 3;
    const int lg = (xcd < r) ? xcd * (q + 1) + pos
                             : r * (q + 1) + (xcd - r) * q + pos;
    const int m0 = (lg % gx) * 128, n0 = (lg / gx) * 128;

    const int kbeg = blockIdx.z * ksplit;
    const int NT = ksplit >> 6;

    const int wr = (wv >> 1) * 64, wc = (wv & 1) * 64;
    const int l15 = lane & 15, g = lane >> 4;
    const int srow = lane >> 3;
    const int sxor = (((lane & 7) ^ srow) << 3);

    const unsigned short* gA0 = A  + (size_t)(m0 + wv * 32 + srow) * K + sxor;
    const unsigned short* gB0 = Bt + (size_t)(n0 + wv * 32 + srow) * K + sxor;

    auto stage = [&](int t) {
        const int b = t & 1;
        const size_t k = (size_t)kbeg + ((size_t)t << 6);
        unsigned short* la = As + b * BUF + (wv * 32) * 64;
        unsigned short* lb = Bs + b * BUF + (wv * 32) * 64;
        #pragma unroll
        for (int c = 0; c < 4; ++c) {
            gl_lds16(gA0 + (size_t)(c * 8) * K + k, la + c * 8 * 64);
            gl_lds16(gB0 + (size_t)(c * 8) * K + k, lb + c * 8 * 64);
        }
    };

    f32x4 acc[4][4] = {};

    stage(0);
    for (int t = 0; t < NT; ++t) {
        if (t + 1 < NT) { stage(t + 1); WAITV(8); }
        else            { WAITV(0); }
        __builtin_amdgcn_s_barrier();

        const unsigned short* Ac = As + (t & 1) * BUF;
        const unsigned short* Bc = Bs + (t & 1) * BUF;
        bf16x8 af[4][2], bfv[4][2];
        #pragma unroll
        for (int mi = 0; mi < 4; ++mi) {
            const int row = wr + mi * 16 + l15, x = row & 7;
            #pragma unroll
            for (int kk = 0; kk < 2; ++kk)
                af[mi][kk] = *(const bf16x8*)(Ac + row * 64 + (((kk * 4 + g) ^ x) << 3));
        }
        #pragma unroll
        for (int ni = 0; ni < 4; ++ni) {
            const int row = wc + ni * 16 + l15, x = row & 7;
            #pragma unroll
            for (int kk = 0; kk < 2; ++kk)
                bfv[ni][kk] = *(const bf16x8*)(Bc + row * 64 + (((kk * 4 + g) ^ x) << 3));
        }
        __builtin_amdgcn_s_setprio(1);
        #pragma unroll
        for (int kk = 0; kk < 2; ++kk)
            #pragma unroll
            for (int mi = 0; mi < 4; ++mi)
                #pragma unroll
                for (int ni = 0; ni < 4; ++ni)
                    acc[mi][ni] = __builtin_amdgcn_mfma_f32_16x16x32_bf16(af[mi][kk], bfv[ni][kk], acc[mi][ni], 0, 0, 0);
        __builtin_amdgcn_s_setprio(0);
        __builtin_amdgcn_s_barrier();
    }

    unsigned short* Cz = Cp + (size_t)blockIdx.z * TT * Ntot;
    #pragma unroll
    for (int mi = 0; mi < 4; ++mi)
        #pragma unroll
        for (int ni = 0; ni < 4; ++ni)
            #pragma unroll
            for (int r2 = 0; r2 < 4; ++r2) {
                int row = m0 + wr + mi * 16 + g * 4 + r2;
                int col = n0 + wc + ni * 16 + l15;
                size_t idx = (size_t)row * Ntot + col;
                float v = acc[mi][ni][r2];
                if (EPI == 0) Cz[idx] = f2b(v);
                else {
                    float z = v > 0.f ? v * v : 0.f;
                    Cz[idx] = f2b(z);
                }
            }
}

// ---------------------------------------------------------------------------
// Fused residual-reduce + RMSNorm: h += sum_z part[z] (bf16 partials), xn = rms(h)
// ---------------------------------------------------------------------------
__global__ __launch_bounds__(256)
void rmsnormF_k(float* __restrict__ h, const unsigned short* __restrict__ part, int nz,
                unsigned short* __restrict__ xn)
{
    const int t = blockIdx.x, tid = threadIdx.x;
    const size_t idx = (size_t)t * (DMODEL / 4) + tid;
    float4 v = ((const float4*)h)[idx];
    for (int z = 0; z < nz; ++z) {
        ushort4 p = ((const ushort4*)part)[idx + (size_t)z * (TT * DMODEL / 4)];
        v.x += b2f(p.x); v.y += b2f(p.y); v.z += b2f(p.z); v.w += b2f(p.w);
    }
    if (nz > 0) ((float4*)h)[idx] = v;

    float ss = v.x*v.x + v.y*v.y + v.z*v.z + v.w*v.w;
    #pragma unroll
    for (int m = 1; m < 64; m <<= 1) ss += __shfl_xor(ss, m);
    __shared__ float red[4];
    if ((tid & 63) == 0) red[tid >> 6] = ss;
    __syncthreads();
    float tot = red[0] + red[1] + red[2] + red[3];
    float rs = rsqrtf(tot * (1.f / DMODEL) + EPSF);
    unsigned short o[4] = { f2b(v.x*rs), f2b(v.y*rs), f2b(v.z*rs), f2b(v.w*rs) };
    *(ushort4*)(xn + (size_t)t * DMODEL + tid * 4) = *(const ushort4*)o;
}

// ---------------------------------------------------------------------------
__global__ __launch_bounds__(256)
void reduce_add_k(float* __restrict__ h, const unsigned short* __restrict__ part, int nz)
{
    const int i = blockIdx.x * 256 + threadIdx.x;
    float4 hv = ((float4*)h)[i];
    for (int z = 0; z < nz; ++z) {
        ushort4 p = ((const ushort4*)part)[i + (size_t)z * (TT * DMODEL / 4)];
        hv.x += b2f(p.x); hv.y += b2f(p.y); hv.z += b2f(p.z); hv.w += b2f(p.w);
    }
    ((float4*)h)[i] = hv;
}

// ---------------------------------------------------------------------------
// Post-QKV (q/k only): sums the 2 bf16 split-K partials, rotary +
// head-RMSNorm on q,k -> bf16. 128 threads, grid 2048. v handled in vtrans2.
// ---------------------------------------------------------------------------
__global__ __launch_bounds__(128)
void post_qkv_k(const unsigned short* __restrict__ qkv,
                const float* __restrict__ cosb, const float* __restrict__ sinb,
                unsigned short* __restrict__ qn, unsigned short* __restrict__ kn)
{
    const size_t S2 = (size_t)TT * 2048;
    const int t = blockIdx.x, tid = threadIdx.x;
    __shared__ float cs[64], sn[64];
    if (tid < 64) { cs[tid] = cosb[t * 64 + tid]; sn[tid] = sinb[t * 64 + tid]; }
    __syncthreads();
    if (tid < 96) {
        const int hid = tid >> 3, sub = tid & 7;
        const unsigned short* src; unsigned short* dst;
        if (hid < 8) { src = qkv + (size_t)t * 2048 + hid * 128;              dst = qn + (size_t)t * 1024 + hid * 128; }
        else         { src = qkv + (size_t)t * 2048 + 1024 + (hid - 8) * 128; dst = kn + (size_t)t * 512 + (hid - 8) * 128; }
        float o1[8], o2[8], ssum = 0.f;
        #pragma unroll
        for (int j = 0; j < 8; ++j) {
            int jj = sub * 8 + j;
            float x1 = b2f(src[jj])      + b2f(src[jj + S2]);
            float x2 = b2f(src[jj + 64]) + b2f(src[jj + 64 + S2]);
            float c = cs[jj], s = sn[jj];
            o1[j] = x1 * c + x2 * s;
            o2[j] = -x1 * s + x2 * c;
            ssum += o1[j]*o1[j] + o2[j]*o2[j];
        }
        ssum += __shfl_xor(ssum, 1); ssum += __shfl_xor(ssum, 2); ssum += __shfl_xor(ssum, 4);
        float rs = rsqrtf(ssum * (1.f / HD) + EPSF);
        #pragma unroll
        for (int j = 0; j < 8; ++j) {
            int jj = sub * 8 + j;
            dst[jj]      = f2b(o1[j] * rs);
            dst[jj + 64] = f2b(o2[j] * rs);
        }
    }
}

// ---------------------------------------------------------------------------
// vtrans2: fused v-compute + transpose. Reads qkv partials (+ ve-gate),
// computes v inline, writes vt [KVD][T] via 64x64 LDS transpose tile.
// grid (32, 8): t0 = bx*64 tokens, c0 = by*64 channels. Each 64-ch tile
// lies in exactly one gate block (c0 is 64-aligned, gates span 128 ch).
// ---------------------------------------------------------------------------
__global__ __launch_bounds__(256)
void vtrans2_k(const unsigned short* __restrict__ qkv, const unsigned short* __restrict__ xn,
               const float* __restrict__ Wgate, const float* __restrict__ vel, int hasve,
               unsigned short* __restrict__ vt)
{
    const size_t S2 = (size_t)TT * 2048;
    __shared__ unsigned short lt[64][72];
    __shared__ float gate_s[64];
    const int t0 = blockIdx.x * 64, c0 = blockIdx.y * 64, tid = threadIdx.x;
    const int gi = c0 >> 7;                     // gate index, constant per block

    if (hasve && tid < 64) {
        const int t = t0 + tid;
        float a = 0.f;
        #pragma unroll
        for (int c = 0; c < 32; ++c) a += b2f(xn[(size_t)t * DMODEL + c]) * Wgate[c * 4 + gi];
        gate_s[tid] = 2.f / (1.f + __expf(-a));
    }
    __syncthreads();

    #pragma unroll
    for (int i = 0; i < 2; ++i) {
        int r = (tid >> 3) + i * 32;            // token offset
        int c = (tid & 7) * 8;                  // channel offset
        const int t = t0 + r, ch = c0 + c;
        size_t off = (size_t)t * 2048 + 1536 + ch;
        bf16x8 pa = *(const bf16x8*)(qkv + off);
        bf16x8 pb = *(const bf16x8*)(qkv + off + S2);
        float g = hasve ? gate_s[r] : 0.f;
        #pragma unroll
        for (int j = 0; j < 8; ++j) {
            float vv = b2f(((unsigned short*)&pa)[j]) + b2f(((unsigned short*)&pb)[j]);
            if (hasve) vv += g * vel[(size_t)t * KVD + ch + j];
            lt[c + j][r] = f2b(vv);
        }
    }
    __syncthreads();
    #pragma unroll
    for (int i = 0; i < 2; ++i) {
        int r = (tid >> 3) + i * 32;
        int c = (tid & 7) * 8;
        *(bf16x8*)(vt + (size_t)(c0 + r) * TT + t0 + c) = *(const bf16x8*)(&lt[r][c]);
    }
}

// ---------------------------------------------------------------------------
// Flash attention, swapped-QK^T form (R9 version — no defer-max).
// ---------------------------------------------------------------------------
__global__ __launch_bounds__(256)
void attn_k(const unsigned short* __restrict__ qn, const unsigned short* __restrict__ kn,
            const unsigned short* __restrict__ vt, unsigned short* __restrict__ y,
            const int* __restrict__ seqlens, int isS)
{
    __shared__ float Ot[4][16][132];
    const int tid = threadIdx.x, w = tid >> 6, lane = tid & 63;
    const int h = blockIdx.y, hkv = h >> 1;
    const int qr = (blockIdx.x * 4 + w) * 16;
    const int s1 = seqlens[1], s2 = seqlens[2], s3 = seqlens[3];
    const int l15 = lane & 15, g = lane >> 4;

    bf16x8 qf[4];
    #pragma unroll
    for (int kk = 0; kk < 4; ++kk)
        qf[kk] = *(const bf16x8*)(qn + (size_t)(qr + l15) * 1024 + h * HD + kk * 32 + g * 8);

    const int row = qr + l15;
    const int drow = (row >= s1) + (row >= s2) + (row >= s3);

    int dq = (qr >= s1) + (qr >= s2) + (qr >= s3);
    int dstart = dq == 0 ? 0 : (dq == 1 ? s1 : (dq == 2 ? s2 : s3));
    int smin = dstart;
    if (isS) { int wlo = qr - WIN; if (wlo > smin) smin = wlo; }
    if (smin < 0) smin = 0;
    const int smax = qr + 16;

    f32x4 acc[8] = {};
    float mrow = -1e30f, lrow = 0.f;

    for (int s0 = smin & ~31; s0 < smax; s0 += 32) {
        f32x4 S[2] = {};
        __builtin_amdgcn_s_setprio(1);
        #pragma unroll
        for (int nb = 0; nb < 2; ++nb) {
            int srow = s0 + nb * 16 + l15;
            #pragma unroll
            for (int kk = 0; kk < 4; ++kk) {
                bf16x8 kf = *(const bf16x8*)(kn + (size_t)srow * KVD + hkv * HD + kk * 32 + g * 8);
                S[nb] = __builtin_amdgcn_mfma_f32_16x16x32_bf16(kf, qf[kk], S[nb], 0, 0, 0);
            }
        }
        __builtin_amdgcn_s_setprio(0);

        float sv[2][4];
        #pragma unroll
        for (int nb = 0; nb < 2; ++nb)
            #pragma unroll
            for (int r = 0; r < 4; ++r) {
                int s = s0 + nb * 16 + 4 * g + r;
                int dcol = (s >= s1) + (s >= s2) + (s >= s3);
                bool valid = (s <= row) && (dcol == drow) && (!isS || (row - s) <= WIN);
                sv[nb][r] = valid ? S[nb][r] * SCALE : -1e30f;
            }

        float pm = sv[0][0];
        #pragma unroll
        for (int r = 1; r < 4; ++r) pm = fmaxf(pm, sv[0][r]);
        #pragma unroll
        for (int r = 0; r < 4; ++r) pm = fmaxf(pm, sv[1][r]);
        pm = fmaxf(pm, __shfl_xor(pm, 16));
        pm = fmaxf(pm, __shfl_xor(pm, 32));
        float mnew = fmaxf(mrow, pm);
        float scl2 = __expf(mrow - mnew);
        float p0[4], p1[4], ps = 0.f;
        #pragma unroll
        for (int r = 0; r < 4; ++r) {
            p0[r] = __expf(sv[0][r] - mnew);
            p1[r] = __expf(sv[1][r] - mnew);
            ps += p0[r] + p1[r];
        }
        ps += __shfl_xor(ps, 16);
        ps += __shfl_xor(ps, 32);
        lrow = lrow * scl2 + ps;
        mrow = mnew;
        #pragma unroll
        for (int nb2 = 0; nb2 < 8; ++nb2) acc[nb2] *= scl2;

        unsigned short pt[8];
        const int base = l15 + ((g & 1) << 5);
        #pragma unroll
        for (int jh = 0; jh < 2; ++jh)
            #pragma unroll
            for (int r = 0; r < 4; ++r) {
                float ta = __shfl(p0[r], base + 16 * jh);
                float tb = __shfl(p1[r], base + 16 * jh);
                pt[jh * 4 + r] = f2b(g >= 2 ? tb : ta);
            }
        bf16x8 pf;
        #pragma unroll
        for (int j = 0; j < 8; ++j) ((unsigned short*)&pf)[j] = pt[j];

        __builtin_amdgcn_s_setprio(1);
        #pragma unroll
        for (int nb2 = 0; nb2 < 8; ++nb2) {
            bf16x8 vf = *(const bf16x8*)(vt + (size_t)(hkv * HD + nb2 * 16 + l15) * TT + s0 + g * 8);
            acc[nb2] = __builtin_amdgcn_mfma_f32_16x16x32_bf16(vf, pf, acc[nb2], 0, 0, 0);
        }
        __builtin_amdgcn_s_setprio(0);
    }

    const float inv = 1.f / lrow;
    #pragma unroll
    for (int nb2 = 0; nb2 < 8; ++nb2)
        #pragma unroll
        for (int r = 0; r < 4; ++r)
            Ot[w][l15][nb2 * 16 + 4 * g + r] = acc[nb2][r] * inv;
    __syncthreads();
    const int qo = lane >> 2, dblk = (lane & 3) * 32;
    #pragma unroll
    for (int i4 = 0; i4 < 4; ++i4) {
        unsigned short ob[8];
        #pragma unroll
        for (int j = 0; j < 8; ++j) ob[j] = f2b(Ot[w][qo][dblk + i4 * 8 + j]);
        *(uint4*)(y + (size_t)(qr + qo) * 1024 + h * HD + dblk + i4 * 8) = *(const uint4*)ob;
    }
}

// ---------------------------------------------------------------------------
extern "C" void kernel_launch(void* const* d_in, const int* in_sizes, int n_in,
                              void* d_out, int out_size, void* d_ws, size_t ws_size,
                              hipStream_t stream)
{
    const float* x       = (const float*)d_in[0];
    const float* ve      = (const float*)d_in[1];
    const float* Wq      = (const float*)d_in[2];
    const float* Wk      = (const float*)d_in[3];
    const float* Wv      = (const float*)d_in[4];
    const float* Wo      = (const float*)d_in[5];
    const float* Wgate   = (const float*)d_in[6];
    const float* Wfc     = (const float*)d_in[7];
    const float* Wproj   = (const float*)d_in[8];
    const float* cosb    = (const float*)d_in[9];
    const float* sinb    = (const float*)d_in[10];
    const int*   seqlens = (const int*)d_in[11];

    float* h = (float*)d_out;
    char* ws = (char*)d_ws;
    unsigned short* xn    = (unsigned short*)(ws);                  // 4 MB
    unsigned short* qn    = (unsigned short*)(ws + (4ull  << 20));  // 4 MB
    unsigned short* kn    = (unsigned short*)(ws + (8ull  << 20));  // 2 MB
    unsigned short* vt    = (unsigned short*)(ws + (12ull << 20));  // 2 MB
    unsigned short* yb    = (unsigned short*)(ws + (14ull << 20));  // 4 MB
    unsigned short* mb    = (unsigned short*)(ws + (18ull << 20));  // 16 MB
    unsigned short* part  = (unsigned short*)(ws + (34ull << 20));  // 16 MB (bf16 partials)
    unsigned short* Bqkv  = (unsigned short*)(ws + (50ull  << 20)); // 32 MB
    unsigned short* Bo    = (unsigned short*)(ws + (82ull  << 20)); // 16 MB
    unsigned short* Bfc   = (unsigned short*)(ws + (98ull  << 20)); // 64 MB
    unsigned short* Bproj = (unsigned short*)(ws + (162ull << 20)); // 64 MB -> 226 MB

    hipMemcpyAsync(h, x, (size_t)TT * DMODEL * sizeof(float), hipMemcpyDeviceToDevice, stream);

    convT_k<<<dim3(704, 8), 512, 0, stream>>>(Wq, Wk, Wv, Wo, Wfc, Wproj,
                                              Bqkv, Bo, Bfc, Bproj);

    for (int l = 0; l < 8; ++l) {
        int hasve = (l % 2) == 1;
        int isS   = (l % 4) != 3;

        rmsnormF_k<<<TT, 256, 0, stream>>>(h, part, l == 0 ? 0 : 4, xn);

        gemm4<0><<<dim3(16, 16, 2), 256, 0, stream>>>(xn, Bqkv + (size_t)l * 2048 * 1024,
                                                      part, 1024, 512, 2048);

        post_qkv_k<<<TT, 128, 0, stream>>>(part, cosb, sinb, qn, kn);

        vtrans2_k<<<dim3(32, 8), 256, 0, stream>>>(part, xn,
            Wgate + (size_t)l * 128, ve + (size_t)l * TT * KVD, hasve, vt);

        attn_k<<<dim3(32, 8), 256, 0, stream>>>(qn, kn, vt, yb, seqlens, isS);

        gemm4<0><<<dim3(16, 8, 4), 256, 0, stream>>>(yb, Bo + (size_t)l * 1024 * 1024,
                                                     part, 1024, 256, 1024);

        rmsnormF_k<<<TT, 256, 0, stream>>>(h, part, 4, xn);

        gemm4<2><<<dim3(16, 32, 1), 256, 0, stream>>>(xn, Bfc + (size_t)l * 4096 * 1024,
                                                      mb, 1024, 1024, 4096);

        gemm4<0><<<dim3(16, 8, 4), 256, 0, stream>>>(mb, Bproj + (size_t)l * 1024 * 4096,
                                                     part, 4096, 1024, 1024);
    }

    reduce_add_k<<<2048, 256, 0, stream>>>(h, part, 4);
}

// Round 15
// 1269.023 us; speedup vs baseline: 1.1983x; 1.0996x over previous
//
#include <hip/hip_runtime.h>
#include <hip/hip_bf16.h>
#include <cstdint>
#include <cstddef>

#define TT     2048
#define DMODEL 1024
#define NHQ    8
#define HD     128
#define KVD    512
#define WIN    384
#define EPSF   1.1920929e-07f
#define SCALE  0.12f

typedef __attribute__((ext_vector_type(8))) short bf16x8;
typedef __attribute__((ext_vector_type(4))) float f32x4;

#define WAITV(N)  asm volatile("s_waitcnt vmcnt(" #N ")" ::: "memory")

__device__ __forceinline__ float b2f(unsigned short u) {
    unsigned int i = ((unsigned int)u) << 16; float f; __builtin_memcpy(&f, &i, 4); return f;
}
__device__ __forceinline__ unsigned short f2b(float f) {
    unsigned int i; __builtin_memcpy(&i, &f, 4);
    unsigned int r = (i + 0x7fffu + ((i >> 16) & 1u)) >> 16;
    return (unsigned short)r;
}

__device__ __forceinline__ void gl_lds16(const unsigned short* g, unsigned short* l) {
    __builtin_amdgcn_global_load_lds(
        (const __attribute__((address_space(1))) unsigned int*)g,
        (__attribute__((address_space(3))) unsigned int*)l, 16, 0, 0);
}
__device__ __forceinline__ void gl_lds16f(const float* g, float* l) {
    __builtin_amdgcn_global_load_lds(
        (const __attribute__((address_space(1))) unsigned int*)g,
        (__attribute__((address_space(3))) unsigned int*)l, 16, 0, 0);
}

// ---------------------------------------------------------------------------
// Weight convert+transpose (R11 version): W f32 [K][N] -> Wt bf16 [N][K].
// ---------------------------------------------------------------------------
__global__ __launch_bounds__(512)
void convT_k(const float* __restrict__ Wq, const float* __restrict__ Wk,
             const float* __restrict__ Wv, const float* __restrict__ Wo,
             const float* __restrict__ Wfc, const float* __restrict__ Wproj,
             unsigned short* __restrict__ Bqkv, unsigned short* __restrict__ Bo,
             unsigned short* __restrict__ Bfc, unsigned short* __restrict__ Bproj)
{
    __shared__ float lt[128 * 128];
    const int bid = blockIdx.x, tid = threadIdx.x, l = blockIdx.y;

    const float* W; unsigned short* Wt; int K, N, t, nbase;
    if (bid < 64)         { W = Wq    + (size_t)l * 1024 * 1024; Wt = Bqkv  + (size_t)l * 2048 * 1024; K = 1024; N = 1024; t = bid;       nbase = 0;    }
    else if (bid < 96)    { W = Wk    + (size_t)l * 1024 * 512;  Wt = Bqkv  + (size_t)l * 2048 * 1024; K = 1024; N = 512;  t = bid - 64;  nbase = 1024; }
    else if (bid < 128)   { W = Wv    + (size_t)l * 1024 * 512;  Wt = Bqkv  + (size_t)l * 2048 * 1024; K = 1024; N = 512;  t = bid - 96;  nbase = 1536; }
    else if (bid < 192)   { W = Wo    + (size_t)l * 1024 * 1024; Wt = Bo    + (size_t)l * 1024 * 1024; K = 1024; N = 1024; t = bid - 128; nbase = 0;    }
    else if (bid < 448)   { W = Wfc   + (size_t)l * 1024 * 4096; Wt = Bfc   + (size_t)l * 4096 * 1024; K = 1024; N = 4096; t = bid - 192; nbase = 0;    }
    else                  { W = Wproj + (size_t)l * 4096 * 1024; Wt = Bproj + (size_t)l * 1024 * 4096; K = 4096; N = 1024; t = bid - 448; nbase = 0;    }

    const int ktiles = K >> 7;
    const int kt0 = (t % ktiles) * 128, nt0 = (t / ktiles) * 128;

    const int lane = tid & 63, w = tid >> 6;
    const int lhi = lane >> 5;
    const int lc  = lane & 31;

    #pragma unroll
    for (int rd = 0; rd < 8; ++rd) {
        const int k = rd * 16 + w * 2 + lhi;
        const int csrc = lc ^ ((k >> 3) & 31);
        const float* src = W + (size_t)(kt0 + k) * N + nt0 + csrc * 4;
        float* dst = lt + (size_t)(rd * 16 + w * 2) * 128;
        gl_lds16f(src, dst);
    }
    __syncthreads();

    #pragma unroll
    for (int i = 0; i < 4; ++i) {
        int flat = i * 512 + tid;
        int n = flat >> 4, kc = (flat & 15) * 8;
        const int c = ((n >> 2) ^ (kc >> 3)) & 31;
        const float* rp = lt + (size_t)kc * 128 + c * 4 + (n & 3);
        unsigned short o[8];
        #pragma unroll
        for (int j = 0; j < 8; ++j) o[j] = f2b(rp[j * 128]);
        *(uint4*)(Wt + (size_t)(nbase + nt0 + n) * K + kt0 + kc) = *(const uint4*)o;
    }
}

// ---------------------------------------------------------------------------
// gemm4 (settled design): 128x128 tile, BK=64, 4 waves, 2 LDS buffers
// (2 blocks/CU), T2 XOR-swizzle, counted vmcnt(8), setprio on MFMA.
// ---------------------------------------------------------------------------
template<int EPI>
__global__ __launch_bounds__(256, 2)
void gemm4(const unsigned short* __restrict__ A, const unsigned short* __restrict__ Bt,
           unsigned short* __restrict__ Cp, int K, int ksplit, int Ntot)
{
    __shared__ unsigned short As[2 * 128 * 64];
    __shared__ unsigned short Bs[2 * 128 * 64];
    const int BUF = 128 * 64;
    const int tid = threadIdx.x, lane = tid & 63, wv = tid >> 6;

    const int gx = gridDim.x;
    const int nwg = gx * gridDim.y;
    const int ihw = blockIdx.y * gx + blockIdx.x;
    const int q = nwg >> 3, r = nwg & 7;
    const int xcd = ihw & 7, pos = ihw >> 3;
    const int lg = (xcd < r) ? xcd * (q + 1) + pos
                             : r * (q + 1) + (xcd - r) * q + pos;
    const int m0 = (lg % gx) * 128, n0 = (lg / gx) * 128;

    const int kbeg = blockIdx.z * ksplit;
    const int NT = ksplit >> 6;

    const int wr = (wv >> 1) * 64, wc = (wv & 1) * 64;
    const int l15 = lane & 15, g = lane >> 4;
    const int srow = lane >> 3;
    const int sxor = (((lane & 7) ^ srow) << 3);

    const unsigned short* gA0 = A  + (size_t)(m0 + wv * 32 + srow) * K + sxor;
    const unsigned short* gB0 = Bt + (size_t)(n0 + wv * 32 + srow) * K + sxor;

    auto stage = [&](int t) {
        const int b = t & 1;
        const size_t k = (size_t)kbeg + ((size_t)t << 6);
        unsigned short* la = As + b * BUF + (wv * 32) * 64;
        unsigned short* lb = Bs + b * BUF + (wv * 32) * 64;
        #pragma unroll
        for (int c = 0; c < 4; ++c) {
            gl_lds16(gA0 + (size_t)(c * 8) * K + k, la + c * 8 * 64);
            gl_lds16(gB0 + (size_t)(c * 8) * K + k, lb + c * 8 * 64);
        }
    };

    f32x4 acc[4][4] = {};

    stage(0);
    for (int t = 0; t < NT; ++t) {
        if (t + 1 < NT) { stage(t + 1); WAITV(8); }
        else            { WAITV(0); }
        __builtin_amdgcn_s_barrier();

        const unsigned short* Ac = As + (t & 1) * BUF;
        const unsigned short* Bc = Bs + (t & 1) * BUF;
        bf16x8 af[4][2], bfv[4][2];
        #pragma unroll
        for (int mi = 0; mi < 4; ++mi) {
            const int row = wr + mi * 16 + l15, x = row & 7;
            #pragma unroll
            for (int kk = 0; kk < 2; ++kk)
                af[mi][kk] = *(const bf16x8*)(Ac + row * 64 + (((kk * 4 + g) ^ x) << 3));
        }
        #pragma unroll
        for (int ni = 0; ni < 4; ++ni) {
            const int row = wc + ni * 16 + l15, x = row & 7;
            #pragma unroll
            for (int kk = 0; kk < 2; ++kk)
                bfv[ni][kk] = *(const bf16x8*)(Bc + row * 64 + (((kk * 4 + g) ^ x) << 3));
        }
        __builtin_amdgcn_s_setprio(1);
        #pragma unroll
        for (int kk = 0; kk < 2; ++kk)
            #pragma unroll
            for (int mi = 0; mi < 4; ++mi)
                #pragma unroll
                for (int ni = 0; ni < 4; ++ni)
                    acc[mi][ni] = __builtin_amdgcn_mfma_f32_16x16x32_bf16(af[mi][kk], bfv[ni][kk], acc[mi][ni], 0, 0, 0);
        __builtin_amdgcn_s_setprio(0);
        __builtin_amdgcn_s_barrier();
    }

    unsigned short* Cz = Cp + (size_t)blockIdx.z * TT * Ntot;
    #pragma unroll
    for (int mi = 0; mi < 4; ++mi)
        #pragma unroll
        for (int ni = 0; ni < 4; ++ni)
            #pragma unroll
            for (int r2 = 0; r2 < 4; ++r2) {
                int row = m0 + wr + mi * 16 + g * 4 + r2;
                int col = n0 + wc + ni * 16 + l15;
                size_t idx = (size_t)row * Ntot + col;
                float v = acc[mi][ni][r2];
                if (EPI == 0) Cz[idx] = f2b(v);
                else {
                    float z = v > 0.f ? v * v : 0.f;
                    Cz[idx] = f2b(z);
                }
            }
}

// ---------------------------------------------------------------------------
__global__ __launch_bounds__(256)
void rmsnormF_k(float* __restrict__ h, const unsigned short* __restrict__ part, int nz,
                unsigned short* __restrict__ xn)
{
    const int t = blockIdx.x, tid = threadIdx.x;
    const size_t idx = (size_t)t * (DMODEL / 4) + tid;
    float4 v = ((const float4*)h)[idx];
    for (int z = 0; z < nz; ++z) {
        ushort4 p = ((const ushort4*)part)[idx + (size_t)z * (TT * DMODEL / 4)];
        v.x += b2f(p.x); v.y += b2f(p.y); v.z += b2f(p.z); v.w += b2f(p.w);
    }
    if (nz > 0) ((float4*)h)[idx] = v;

    float ss = v.x*v.x + v.y*v.y + v.z*v.z + v.w*v.w;
    #pragma unroll
    for (int m = 1; m < 64; m <<= 1) ss += __shfl_xor(ss, m);
    __shared__ float red[4];
    if ((tid & 63) == 0) red[tid >> 6] = ss;
    __syncthreads();
    float tot = red[0] + red[1] + red[2] + red[3];
    float rs = rsqrtf(tot * (1.f / DMODEL) + EPSF);
    unsigned short o[4] = { f2b(v.x*rs), f2b(v.y*rs), f2b(v.z*rs), f2b(v.w*rs) };
    *(ushort4*)(xn + (size_t)t * DMODEL + tid * 4) = *(const ushort4*)o;
}

// ---------------------------------------------------------------------------
__global__ __launch_bounds__(256)
void reduce_add_k(float* __restrict__ h, const unsigned short* __restrict__ part, int nz)
{
    const int i = blockIdx.x * 256 + threadIdx.x;
    float4 hv = ((float4*)h)[i];
    for (int z = 0; z < nz; ++z) {
        ushort4 p = ((const ushort4*)part)[i + (size_t)z * (TT * DMODEL / 4)];
        hv.x += b2f(p.x); hv.y += b2f(p.y); hv.z += b2f(p.z); hv.w += b2f(p.w);
    }
    ((float4*)h)[i] = hv;
}

// ---------------------------------------------------------------------------
// Post-QKV (q/k only): sums the 2 bf16 split-K partials, rotary +
// head-RMSNorm on q,k -> bf16. 128 threads, grid 2048.
// ---------------------------------------------------------------------------
__global__ __launch_bounds__(128)
void post_qkv_k(const unsigned short* __restrict__ qkv,
                const float* __restrict__ cosb, const float* __restrict__ sinb,
                unsigned short* __restrict__ qn, unsigned short* __restrict__ kn)
{
    const size_t S2 = (size_t)TT * 2048;
    const int t = blockIdx.x, tid = threadIdx.x;
    __shared__ float cs[64], sn[64];
    if (tid < 64) { cs[tid] = cosb[t * 64 + tid]; sn[tid] = sinb[t * 64 + tid]; }
    __syncthreads();
    if (tid < 96) {
        const int hid = tid >> 3, sub = tid & 7;
        const unsigned short* src; unsigned short* dst;
        if (hid < 8) { src = qkv + (size_t)t * 2048 + hid * 128;              dst = qn + (size_t)t * 1024 + hid * 128; }
        else         { src = qkv + (size_t)t * 2048 + 1024 + (hid - 8) * 128; dst = kn + (size_t)t * 512 + (hid - 8) * 128; }
        float o1[8], o2[8], ssum = 0.f;
        #pragma unroll
        for (int j = 0; j < 8; ++j) {
            int jj = sub * 8 + j;
            float x1 = b2f(src[jj])      + b2f(src[jj + S2]);
            float x2 = b2f(src[jj + 64]) + b2f(src[jj + 64 + S2]);
            float c = cs[jj], s = sn[jj];
            o1[j] = x1 * c + x2 * s;
            o2[j] = -x1 * s + x2 * c;
            ssum += o1[j]*o1[j] + o2[j]*o2[j];
        }
        ssum += __shfl_xor(ssum, 1); ssum += __shfl_xor(ssum, 2); ssum += __shfl_xor(ssum, 4);
        float rs = rsqrtf(ssum * (1.f / HD) + EPSF);
        #pragma unroll
        for (int j = 0; j < 8; ++j) {
            int jj = sub * 8 + j;
            dst[jj]      = f2b(o1[j] * rs);
            dst[jj + 64] = f2b(o2[j] * rs);
        }
    }
}

// ---------------------------------------------------------------------------
// vtrans2: fused v-compute + transpose (R14 version).
// ---------------------------------------------------------------------------
__global__ __launch_bounds__(256)
void vtrans2_k(const unsigned short* __restrict__ qkv, const unsigned short* __restrict__ xn,
               const float* __restrict__ Wgate, const float* __restrict__ vel, int hasve,
               unsigned short* __restrict__ vt)
{
    const size_t S2 = (size_t)TT * 2048;
    __shared__ unsigned short lt[64][72];
    __shared__ float gate_s[64];
    const int t0 = blockIdx.x * 64, c0 = blockIdx.y * 64, tid = threadIdx.x;
    const int gi = c0 >> 7;

    if (hasve && tid < 64) {
        const int t = t0 + tid;
        float a = 0.f;
        #pragma unroll
        for (int c = 0; c < 32; ++c) a += b2f(xn[(size_t)t * DMODEL + c]) * Wgate[c * 4 + gi];
        gate_s[tid] = 2.f / (1.f + __expf(-a));
    }
    __syncthreads();

    #pragma unroll
    for (int i = 0; i < 2; ++i) {
        int r = (tid >> 3) + i * 32;
        int c = (tid & 7) * 8;
        const int t = t0 + r, ch = c0 + c;
        size_t off = (size_t)t * 2048 + 1536 + ch;
        bf16x8 pa = *(const bf16x8*)(qkv + off);
        bf16x8 pb = *(const bf16x8*)(qkv + off + S2);
        float g = hasve ? gate_s[r] : 0.f;
        #pragma unroll
        for (int j = 0; j < 8; ++j) {
            float vv = b2f(((unsigned short*)&pa)[j]) + b2f(((unsigned short*)&pb)[j]);
            if (hasve) vv += g * vel[(size_t)t * KVD + ch + j];
            lt[c + j][r] = f2b(vv);
        }
    }
    __syncthreads();
    #pragma unroll
    for (int i = 0; i < 2; ++i) {
        int r = (tid >> 3) + i * 32;
        int c = (tid & 7) * 8;
        *(bf16x8*)(vt + (size_t)(c0 + r) * TT + t0 + c) = *(const bf16x8*)(&lt[r][c]);
    }
}

// ---------------------------------------------------------------------------
// Flash attention, split-S (blockIdx.z halves the tile range -> 2x waves).
// Writes unnormalized f32 acc + (m,l) per row; merge kernel combines.
// Per-lane validity guard: a fully-masked tile for a row contributes 0
// (needed because a split sub-range may contain no valid cols for a row).
// ---------------------------------------------------------------------------
__global__ __launch_bounds__(256)
void attn_k(const unsigned short* __restrict__ qn, const unsigned short* __restrict__ kn,
            const unsigned short* __restrict__ vt,
            float* __restrict__ pacc, float* __restrict__ pml,
            const int* __restrict__ seqlens, int isS)
{
    const int tid = threadIdx.x, w = tid >> 6, lane = tid & 63;
    const int h = blockIdx.y, hkv = h >> 1, z = blockIdx.z;
    const int qr = (blockIdx.x * 4 + w) * 16;
    const int s1 = seqlens[1], s2 = seqlens[2], s3 = seqlens[3];
    const int l15 = lane & 15, g = lane >> 4;

    const int row = qr + l15;
    const int drow = (row >= s1) + (row >= s2) + (row >= s3);

    int dq = (qr >= s1) + (qr >= s2) + (qr >= s3);
    int dstart = dq == 0 ? 0 : (dq == 1 ? s1 : (dq == 2 ? s2 : s3));
    int smin = dstart;
    if (isS) { int wlo = qr - WIN; if (wlo > smin) smin = wlo; }
    if (smin < 0) smin = 0;
    const int smax = qr + 16;

    const int base0 = smin & ~31;
    const int ntiles = (smax - base0 + 31) >> 5;
    const int tp = (ntiles + 1) >> 1;
    const int tbeg = z ? tp : 0, tend = z ? ntiles : tp;

    const size_t rowi = ((size_t)z * NHQ + h) * TT + row;

    if (tbeg >= tend) {                       // empty split: mark l=0
        if (lane < 16) { pml[rowi * 2] = -1e30f; pml[rowi * 2 + 1] = 0.f; }
        return;
    }

    bf16x8 qf[4];
    #pragma unroll
    for (int kk = 0; kk < 4; ++kk)
        qf[kk] = *(const bf16x8*)(qn + (size_t)(qr + l15) * 1024 + h * HD + kk * 32 + g * 8);

    f32x4 acc[8] = {};
    float mrow = -1e30f, lrow = 0.f;

    for (int tt = tbeg; tt < tend; ++tt) {
        const int s0 = base0 + tt * 32;
        f32x4 S[2] = {};
        __builtin_amdgcn_s_setprio(1);
        #pragma unroll
        for (int nb = 0; nb < 2; ++nb) {
            int srow = s0 + nb * 16 + l15;
            #pragma unroll
            for (int kk = 0; kk < 4; ++kk) {
                bf16x8 kf = *(const bf16x8*)(kn + (size_t)srow * KVD + hkv * HD + kk * 32 + g * 8);
                S[nb] = __builtin_amdgcn_mfma_f32_16x16x32_bf16(kf, qf[kk], S[nb], 0, 0, 0);
            }
        }
        __builtin_amdgcn_s_setprio(0);

        float sv[2][4];
        #pragma unroll
        for (int nb = 0; nb < 2; ++nb)
            #pragma unroll
            for (int r = 0; r < 4; ++r) {
                int s = s0 + nb * 16 + 4 * g + r;
                int dcol = (s >= s1) + (s >= s2) + (s >= s3);
                bool valid = (s <= row) && (dcol == drow) && (!isS || (row - s) <= WIN);
                sv[nb][r] = valid ? S[nb][r] * SCALE : -1e30f;
            }

        float pm = sv[0][0];
        #pragma unroll
        for (int r = 1; r < 4; ++r) pm = fmaxf(pm, sv[0][r]);
        #pragma unroll
        for (int r = 0; r < 4; ++r) pm = fmaxf(pm, sv[1][r]);
        pm = fmaxf(pm, __shfl_xor(pm, 16));
        pm = fmaxf(pm, __shfl_xor(pm, 32));
        float mnew = fmaxf(mrow, pm);
        const float vany = (mnew > -1e29f) ? 1.f : 0.f;   // row has any valid col so far
        float scl2 = __expf(mrow - mnew);
        float p0[4], p1[4], ps = 0.f;
        #pragma unroll
        for (int r = 0; r < 4; ++r) {
            p0[r] = vany * __expf(sv[0][r] - mnew);
            p1[r] = vany * __expf(sv[1][r] - mnew);
            ps += p0[r] + p1[r];
        }
        ps += __shfl_xor(ps, 16);
        ps += __shfl_xor(ps, 32);
        lrow = lrow * scl2 + ps;
        mrow = mnew;
        #pragma unroll
        for (int nb2 = 0; nb2 < 8; ++nb2) acc[nb2] *= scl2;

        unsigned short pt[8];
        const int base = l15 + ((g & 1) << 5);
        #pragma unroll
        for (int jh = 0; jh < 2; ++jh)
            #pragma unroll
            for (int r = 0; r < 4; ++r) {
                float ta = __shfl(p0[r], base + 16 * jh);
                float tb = __shfl(p1[r], base + 16 * jh);
                pt[jh * 4 + r] = f2b(g >= 2 ? tb : ta);
            }
        bf16x8 pf;
        #pragma unroll
        for (int j = 0; j < 8; ++j) ((unsigned short*)&pf)[j] = pt[j];

        __builtin_amdgcn_s_setprio(1);
        #pragma unroll
        for (int nb2 = 0; nb2 < 8; ++nb2) {
            bf16x8 vf = *(const bf16x8*)(vt + (size_t)(hkv * HD + nb2 * 16 + l15) * TT + s0 + g * 8);
            acc[nb2] = __builtin_amdgcn_mfma_f32_16x16x32_bf16(vf, pf, acc[nb2], 0, 0, 0);
        }
        __builtin_amdgcn_s_setprio(0);
    }

    // write unnormalized acc (lane holds O^T[d = nb2*16+4g+r][q=l15]) + m,l
    float* pa = pacc + rowi * HD;
    #pragma unroll
    for (int nb2 = 0; nb2 < 8; ++nb2)
        *(float4*)(pa + nb2 * 16 + 4 * g) = *(float4*)&acc[nb2];
    if (lane < 16) { pml[rowi * 2] = mrow; pml[rowi * 2 + 1] = lrow; }
}

// ---------------------------------------------------------------------------
// attn merge: combine the 2 split-S partials; write bf16 y.
// grid = T blocks x 256 thr; thread -> (head = tid>>5, d-group = (tid&31)*4).
// ---------------------------------------------------------------------------
__global__ __launch_bounds__(256)
void attn_merge_k(const float* __restrict__ pacc, const float* __restrict__ pml,
                  unsigned short* __restrict__ y)
{
    const int r = blockIdx.x, tid = threadIdx.x;
    const int h = tid >> 5, dg = (tid & 31) * 4;
    const size_t i1 = ((size_t)0 * NHQ + h) * TT + r;
    const size_t i2 = ((size_t)1 * NHQ + h) * TT + r;
    const float m1 = pml[i1 * 2], l1 = pml[i1 * 2 + 1];
    const float m2 = pml[i2 * 2], l2 = pml[i2 * 2 + 1];
    const float M = fmaxf(m1, m2);
    const float w1 = (l1 > 0.f) ? __expf(m1 - M) : 0.f;
    const float w2 = (l2 > 0.f) ? __expf(m2 - M) : 0.f;
    const float inv = 1.f / (w1 * l1 + w2 * l2);

    float4 a1 = {0.f, 0.f, 0.f, 0.f}, a2 = {0.f, 0.f, 0.f, 0.f};
    if (l1 > 0.f) a1 = *(const float4*)(pacc + i1 * HD + dg);
    if (l2 > 0.f) a2 = *(const float4*)(pacc + i2 * HD + dg);

    unsigned short o[4];
    o[0] = f2b((w1 * a1.x + w2 * a2.x) * inv);
    o[1] = f2b((w1 * a1.y + w2 * a2.y) * inv);
    o[2] = f2b((w1 * a1.z + w2 * a2.z) * inv);
    o[3] = f2b((w1 * a1.w + w2 * a2.w) * inv);
    *(ushort4*)(y + (size_t)r * 1024 + h * HD + dg) = *(const ushort4*)o;
}

// ---------------------------------------------------------------------------
extern "C" void kernel_launch(void* const* d_in, const int* in_sizes, int n_in,
                              void* d_out, int out_size, void* d_ws, size_t ws_size,
                              hipStream_t stream)
{
    const float* x       = (const float*)d_in[0];
    const float* ve      = (const float*)d_in[1];
    const float* Wq      = (const float*)d_in[2];
    const float* Wk      = (const float*)d_in[3];
    const float* Wv      = (const float*)d_in[4];
    const float* Wo      = (const float*)d_in[5];
    const float* Wgate   = (const float*)d_in[6];
    const float* Wfc     = (const float*)d_in[7];
    const float* Wproj   = (const float*)d_in[8];
    const float* cosb    = (const float*)d_in[9];
    const float* sinb    = (const float*)d_in[10];
    const int*   seqlens = (const int*)d_in[11];

    float* h = (float*)d_out;
    char* ws = (char*)d_ws;
    unsigned short* xn    = (unsigned short*)(ws);                  // 4 MB
    unsigned short* qn    = (unsigned short*)(ws + (4ull  << 20));  // 4 MB
    unsigned short* kn    = (unsigned short*)(ws + (8ull  << 20));  // 2 MB
    unsigned short* vt    = (unsigned short*)(ws + (12ull << 20));  // 2 MB
    unsigned short* yb    = (unsigned short*)(ws + (14ull << 20));  // 4 MB
    unsigned short* mb    = (unsigned short*)(ws + (18ull << 20));  // 16 MB
    unsigned short* part  = (unsigned short*)(ws + (34ull << 20));  // 16 MB (bf16 partials)
    float*          pacc  = (float*)(ws + (50ull << 20));           // 16 MB
    float*          pml   = (float*)(ws + (66ull << 20));           // 0.25 MB
    unsigned short* Bqkv  = (unsigned short*)(ws + (68ull  << 20)); // 32 MB
    unsigned short* Bo    = (unsigned short*)(ws + (100ull << 20)); // 16 MB
    unsigned short* Bfc   = (unsigned short*)(ws + (116ull << 20)); // 64 MB
    unsigned short* Bproj = (unsigned short*)(ws + (180ull << 20)); // 64 MB -> 244 MB

    hipMemcpyAsync(h, x, (size_t)TT * DMODEL * sizeof(float), hipMemcpyDeviceToDevice, stream);

    convT_k<<<dim3(704, 8), 512, 0, stream>>>(Wq, Wk, Wv, Wo, Wfc, Wproj,
                                              Bqkv, Bo, Bfc, Bproj);

    for (int l = 0; l < 8; ++l) {
        int hasve = (l % 2) == 1;
        int isS   = (l % 4) != 3;

        rmsnormF_k<<<TT, 256, 0, stream>>>(h, part, l == 0 ? 0 : 4, xn);

        gemm4<0><<<dim3(16, 16, 2), 256, 0, stream>>>(xn, Bqkv + (size_t)l * 2048 * 1024,
                                                      part, 1024, 512, 2048);

        post_qkv_k<<<TT, 128, 0, stream>>>(part, cosb, sinb, qn, kn);

        vtrans2_k<<<dim3(32, 8), 256, 0, stream>>>(part, xn,
            Wgate + (size_t)l * 128, ve + (size_t)l * TT * KVD, hasve, vt);

        attn_k<<<dim3(32, 8, 2), 256, 0, stream>>>(qn, kn, vt, pacc, pml, seqlens, isS);
        attn_merge_k<<<TT, 256, 0, stream>>>(pacc, pml, yb);

        gemm4<0><<<dim3(16, 8, 4), 256, 0, stream>>>(yb, Bo + (size_t)l * 1024 * 1024,
                                                     part, 1024, 256, 1024);

        rmsnormF_k<<<TT, 256, 0, stream>>>(h, part, 4, xn);

        gemm4<2><<<dim3(16, 32, 1), 256, 0, stream>>>(xn, Bfc + (size_t)l * 4096 * 1024,
                                                      mb, 1024, 1024, 4096);

        gemm4<0><<<dim3(16, 8, 4), 256, 0, stream>>>(mb, Bproj + (size_t)l * 1024 * 4096,
                                                     part, 4096, 1024, 1024);
    }

    reduce_add_k<<<2048, 256, 0, stream>>>(h, part, 4);
}